// Round 2
// baseline (921.185 us; speedup 1.0000x reference)
//
#include <hip/hip_runtime.h>
#include <hip/hip_bf16.h>
#include <cstdint>

typedef __bf16 bf16x8 __attribute__((ext_vector_type(8)));
typedef float f32x4 __attribute__((ext_vector_type(4)));

union U128 { uint4 u; __bf16 h[8]; };
union U64  { uint2 u; __bf16 h[4]; };

#define DMODEL 1024
#define NHEAD  16
#define DHEAD  64

// ---------------- fp32 -> bf16 cast ----------------
__global__ __launch_bounds__(256) void k_cast(const float* __restrict__ s,
    __bf16* __restrict__ d, int n) {
  int i = (blockIdx.x * 256 + threadIdx.x) * 4;
  if (i < n) {
    float4 v = *(const float4*)(s + i);
    U64 o;
    o.h[0] = (__bf16)v.x; o.h[1] = (__bf16)v.y;
    o.h[2] = (__bf16)v.z; o.h[3] = (__bf16)v.w;
    *(uint2*)(d + i) = o.u;
  }
}

// ------------- batched 32x32 transpose + cast: src[z][R][C] f32 -> dst[z][C][R] bf16 -------------
__global__ __launch_bounds__(256) void k_transpose(const float* __restrict__ src,
    __bf16* __restrict__ dst, int R, int C) {
  __shared__ __bf16 tile[32][33];
  src += (size_t)blockIdx.z * R * C;
  dst += (size_t)blockIdx.z * R * C;
  int c0 = blockIdx.x * 32, r0 = blockIdx.y * 32;
  int tx = threadIdx.x & 31, ty = threadIdx.x >> 5;
  for (int i = ty; i < 32; i += 8)
    tile[i][tx] = (__bf16)src[(size_t)(r0 + i) * C + (c0 + tx)];
  __syncthreads();
  for (int i = ty; i < 32; i += 8)
    dst[(size_t)(c0 + i) * R + (r0 + tx)] = tile[tx][i];
}

// ---------------- bf16 TN GEMM: C[M,N] = A[M,K] * Bt[N,K]^T + bias ----------------
// 128x128 tile, BK=32, 4 waves each 64x64 via 4x4 mfma_16x16x32_bf16
template<bool RELU, typename OutT>
__global__ __launch_bounds__(256, 2) void k_gemm(const __bf16* __restrict__ A,
    const __bf16* __restrict__ Bt, const float* __restrict__ bias,
    OutT* __restrict__ C, int M, int N, int K) {
  __shared__ alignas(16) __bf16 As[128][56];   // stride 112B: 16B aligned
  __shared__ alignas(16) __bf16 Bs[128][56];
  const int m0 = blockIdx.y * 128, n0 = blockIdx.x * 128;
  const int t = threadIdx.x;
  const int wave = t >> 6, lane = t & 63;
  const int wm = (wave & 1) * 64, wn = (wave >> 1) * 64;
  const int lrow = lane & 15, quad = lane >> 4;
  const int srow = t >> 2, scol = (t & 3) * 8;
  const __bf16* Ap  = A  + (size_t)(m0 + srow) * K + scol;
  const __bf16* Ap2 = Ap + (size_t)64 * K;
  const __bf16* Bp  = Bt + (size_t)(n0 + srow) * K + scol;
  const __bf16* Bp2 = Bp + (size_t)64 * K;
  f32x4 acc[4][4] = {};
  for (int k0 = 0; k0 < K; k0 += 32) {
    uint4 a1 = *(const uint4*)(Ap  + k0);
    uint4 a2 = *(const uint4*)(Ap2 + k0);
    uint4 b1 = *(const uint4*)(Bp  + k0);
    uint4 b2 = *(const uint4*)(Bp2 + k0);
    __syncthreads();
    *(uint4*)&As[srow][scol]      = a1;
    *(uint4*)&As[srow + 64][scol] = a2;
    *(uint4*)&Bs[srow][scol]      = b1;
    *(uint4*)&Bs[srow + 64][scol] = b2;
    __syncthreads();
    bf16x8 af[4], bfv[4];
    for (int i = 0; i < 4; i++) {
      af[i]  = *(const bf16x8*)&As[wm + i * 16 + lrow][quad * 8];
      bfv[i] = *(const bf16x8*)&Bs[wn + i * 16 + lrow][quad * 8];
    }
    for (int mi = 0; mi < 4; mi++)
      for (int ni = 0; ni < 4; ni++)
        acc[mi][ni] = __builtin_amdgcn_mfma_f32_16x16x32_bf16(af[mi], bfv[ni], acc[mi][ni], 0, 0, 0);
  }
  for (int ni = 0; ni < 4; ni++) {
    int col = n0 + wn + ni * 16 + lrow;
    float bv = bias[col];
    for (int mi = 0; mi < 4; mi++) {
      int row = m0 + wm + mi * 16 + quad * 4;
      for (int r = 0; r < 4; r++) {
        float v = acc[mi][ni][r] + bv;
        if (RELU) v = fmaxf(v, 0.f);
        C[(size_t)(row + r) * N + col] = (OutT)v;
      }
    }
  }
}

// ---------------- fused flash-style attention ----------------
// grid (Lq/64, B*H); Q/K/V bf16 layout [B, L, H*64]; O fp32 same layout
template<bool CAUSAL>
__global__ __launch_bounds__(256, 2) void k_attn(const __bf16* __restrict__ Q,
    const __bf16* __restrict__ Kg, const __bf16* __restrict__ Vg,
    float* __restrict__ O, int Lq, int Lk) {
  __shared__ alignas(16) __bf16 Qs[64][72];
  __shared__ alignas(16) __bf16 Ks[64][72];
  __shared__ alignas(16) __bf16 Vt[64][72];   // transposed: [vd][k]
  __shared__ alignas(16) __bf16 Ps[64][72];
  __shared__ alignas(16) float  Ss[64][68];
  __shared__ float  pmax_s[64][4], psum_s[64][4];
  __shared__ float  mnew_s[64], alpha_s[64], linv_s[64];
  const int t = threadIdx.x;
  const int wave = t >> 6, lane = t & 63;
  const int lrow = lane & 15, quad = lane >> 4;
  const int wm16 = wave * 16;
  const int qt = blockIdx.x, q0 = qt * 64;
  const int b = blockIdx.y >> 4, h = blockIdx.y & 15;
  const __bf16* Qb = Q  + (size_t)b * Lq * DMODEL + h * DHEAD;
  const __bf16* Kb = Kg + (size_t)b * Lk * DMODEL + h * DHEAD;
  const __bf16* Vb = Vg + (size_t)b * Lk * DMODEL + h * DHEAD;
  {
    int row = t >> 3, col = (t & 7) * 8;
    *(uint4*)&Qs[row][col]      = *(const uint4*)(Qb + (size_t)(q0 + row) * DMODEL + col);
    *(uint4*)&Qs[row + 32][col] = *(const uint4*)(Qb + (size_t)(q0 + row + 32) * DMODEL + col);
  }
  f32x4 acc_o[4] = {};
  float m_reg = -1e30f, l_reg = 0.f, alpha_reg = 0.f;
  const float scale = 0.125f;  // 1/sqrt(64)
  const int nkt = CAUSAL ? (qt + 1) : (Lk / 64);
  const int krow = t >> 3, kcol = (t & 7) * 8;
  const int vkk = t & 63, vd8 = t >> 6;
  for (int kt = 0; kt < nkt; kt++) {
    const int k0 = kt * 64;
    uint4 ka  = *(const uint4*)(Kb + (size_t)(k0 + krow) * DMODEL + kcol);
    uint4 ka2 = *(const uint4*)(Kb + (size_t)(k0 + krow + 32) * DMODEL + kcol);
    uint4 va  = *(const uint4*)(Vb + (size_t)(k0 + vkk) * DMODEL + vd8 * 8);
    uint4 va2 = *(const uint4*)(Vb + (size_t)(k0 + vkk) * DMODEL + (vd8 + 4) * 8);
    __syncthreads();   // prior iteration done with Ks/Vt
    *(uint4*)&Ks[krow][kcol]      = ka;
    *(uint4*)&Ks[krow + 32][kcol] = ka2;
    { U128 u; u.u = va;  for (int j = 0; j < 8; j++) Vt[vd8 * 8 + j][vkk] = u.h[j]; }
    { U128 u; u.u = va2; for (int j = 0; j < 8; j++) Vt[(vd8 + 4) * 8 + j][vkk] = u.h[j]; }
    __syncthreads();
    // S = Q K^T  (each wave: 16 q-rows x 64 cols)
    f32x4 accs[4] = {};
    for (int ks = 0; ks < 2; ks++) {
      bf16x8 qa = *(const bf16x8*)&Qs[wm16 + lrow][ks * 32 + quad * 8];
      for (int nb = 0; nb < 4; nb++) {
        bf16x8 kfr = *(const bf16x8*)&Ks[nb * 16 + lrow][ks * 32 + quad * 8];
        accs[nb] = __builtin_amdgcn_mfma_f32_16x16x32_bf16(qa, kfr, accs[nb], 0, 0, 0);
      }
    }
    for (int nb = 0; nb < 4; nb++)
      for (int r = 0; r < 4; r++)
        Ss[wm16 + quad * 4 + r][nb * 16 + lrow] = accs[nb][r];
    __syncthreads();
    // partial row max
    {
      const int r = t >> 2, g = t & 3;
      const bool diag = CAUSAL && (kt == qt);
      float pm = -3e38f;
      for (int j = 0; j < 16; j++) {
        int c = g * 16 + j;
        if (!diag || c <= r) pm = fmaxf(pm, Ss[r][c]);
      }
      pmax_s[r][g] = pm;
    }
    __syncthreads();
    // online-softmax state update (row owners)
    if (t < 64) {
      float pm = fmaxf(fmaxf(pmax_s[t][0], pmax_s[t][1]), fmaxf(pmax_s[t][2], pmax_s[t][3]));
      float mnew = fmaxf(m_reg, pm * scale);
      alpha_reg = expf(fminf(m_reg - mnew, 0.f));
      m_reg = mnew;
      mnew_s[t] = mnew;
      alpha_s[t] = alpha_reg;
    }
    __syncthreads();
    // P = exp(S*scale - m_new), partial sums; rescale O accumulators
    {
      const int r = t >> 2, g = t & 3;
      const bool diag = CAUSAL && (kt == qt);
      float mn = mnew_s[r];
      float ps = 0.f;
      U128 w0, w1;
      for (int j = 0; j < 16; j++) {
        int c = g * 16 + j;
        float p = 0.f;
        if (!diag || c <= r) { p = expf(fminf(Ss[r][c] * scale - mn, 0.f)); ps += p; }
        if (j < 8) w0.h[j] = (__bf16)p; else w1.h[j - 8] = (__bf16)p;
      }
      *(uint4*)&Ps[r][g * 16]     = w0.u;
      *(uint4*)&Ps[r][g * 16 + 8] = w1.u;
      psum_s[r][g] = ps;
    }
    {
      float al0 = alpha_s[wm16 + quad * 4 + 0];
      float al1 = alpha_s[wm16 + quad * 4 + 1];
      float al2 = alpha_s[wm16 + quad * 4 + 2];
      float al3 = alpha_s[wm16 + quad * 4 + 3];
      for (int ni = 0; ni < 4; ni++) {
        acc_o[ni][0] *= al0; acc_o[ni][1] *= al1;
        acc_o[ni][2] *= al2; acc_o[ni][3] *= al3;
      }
    }
    __syncthreads();
    if (t < 64)
      l_reg = l_reg * alpha_reg + (psum_s[t][0] + psum_s[t][1] + psum_s[t][2] + psum_s[t][3]);
    // O += P V
    for (int ks = 0; ks < 2; ks++) {
      bf16x8 pa = *(const bf16x8*)&Ps[wm16 + lrow][ks * 32 + quad * 8];
      for (int ni = 0; ni < 4; ni++) {
        bf16x8 vfr = *(const bf16x8*)&Vt[ni * 16 + lrow][ks * 32 + quad * 8];
        acc_o[ni] = __builtin_amdgcn_mfma_f32_16x16x32_bf16(pa, vfr, acc_o[ni], 0, 0, 0);
      }
    }
  }
  if (t < 64) linv_s[t] = 1.f / fmaxf(l_reg, 1e-30f);
  __syncthreads();
  float* Ob = O + (size_t)b * Lq * DMODEL + h * DHEAD;
  for (int ni = 0; ni < 4; ni++)
    for (int r = 0; r < 4; r++) {
      int q = wm16 + quad * 4 + r;
      Ob[(size_t)(q0 + q) * DMODEL + ni * 16 + lrow] = acc_o[ni][r] * linv_s[q];
    }
}

// ---------------- residual(ResT + fp32) + LayerNorm -> OutT ----------------
template<typename ResT, typename OutT>
__global__ __launch_bounds__(256) void k_ln_add(const ResT* __restrict__ a,
    const float* __restrict__ bres, const float* __restrict__ g,
    const float* __restrict__ be, OutT* __restrict__ out) {
  __shared__ float red[2][4];
  const int r = blockIdx.x, t = threadIdx.x;
  const size_t base = (size_t)r * DMODEL + t * 4;
  float x[4];
  for (int i = 0; i < 4; i++) x[i] = (float)a[base + i] + bres[base + i];
  float s  = x[0] + x[1] + x[2] + x[3];
  float s2 = x[0]*x[0] + x[1]*x[1] + x[2]*x[2] + x[3]*x[3];
  for (int off = 32; off > 0; off >>= 1) {
    s  += __shfl_down(s, off);
    s2 += __shfl_down(s2, off);
  }
  if ((t & 63) == 0) { red[0][t >> 6] = s; red[1][t >> 6] = s2; }
  __syncthreads();
  s  = red[0][0] + red[0][1] + red[0][2] + red[0][3];
  s2 = red[1][0] + red[1][1] + red[1][2] + red[1][3];
  const float mean = s * (1.f / DMODEL);
  const float var  = s2 * (1.f / DMODEL) - mean * mean;
  const float rstd = rsqrtf(var + 1e-5f);
  for (int i = 0; i < 4; i++)
    out[base + i] = (OutT)((x[i] - mean) * rstd * g[t * 4 + i] + be[t * 4 + i]);
}

extern "C" void kernel_launch(void* const* d_in, const int* in_sizes, int n_in,
                              void* d_out, int out_size, void* d_ws, size_t ws_size,
                              hipStream_t stream) {
  (void)in_sizes; (void)n_in; (void)out_size; (void)ws_size;
  const float* dec   = (const float*)d_in[0];
  const float* enc   = (const float*)d_in[1];
  const float* m_wq  = (const float*)d_in[2];
  const float* m_bq  = (const float*)d_in[3];
  const float* m_wk  = (const float*)d_in[4];
  const float* m_bk  = (const float*)d_in[5];
  const float* m_wv  = (const float*)d_in[6];
  const float* m_bv  = (const float*)d_in[7];
  const float* c_wq  = (const float*)d_in[8];
  const float* c_bq  = (const float*)d_in[9];
  const float* c_wk  = (const float*)d_in[10];
  const float* c_bk  = (const float*)d_in[11];
  const float* c_wv  = (const float*)d_in[12];
  const float* c_bv  = (const float*)d_in[13];
  const float* ff_w1 = (const float*)d_in[14];
  const float* ff_b1 = (const float*)d_in[15];
  const float* ff_w2 = (const float*)d_in[16];
  const float* ff_b2 = (const float*)d_in[17];
  const float* ln1_g = (const float*)d_in[18];
  const float* ln1_b = (const float*)d_in[19];
  const float* ln2_g = (const float*)d_in[20];
  const float* ln2_b = (const float*)d_in[21];

  // workspace layout (peak 136 MB), sequential reuse:
  //  [0,16)    decB (bf16 dec)  -> later X1b
  //  [16,32)   encB (bf16 enc)  -> later X2b
  //  [32,40)   WB   (bf16 transposed weights)
  //  [40,56)   Qb | [56,72) Kb | [72,88) Vb   (attention phases)
  //  [40,104)  FF   (bf16, FFN phase; Q/K/V dead)
  //  [104,136) AO   (fp32 attention/FF2 output)
  char* w = (char*)d_ws;
  __bf16* decB = (__bf16*)(w);
  __bf16* encB = (__bf16*)(w + (16ull << 20));
  __bf16* X1b  = decB;
  __bf16* X2b  = encB;
  __bf16* WB   = (__bf16*)(w + (32ull << 20));
  __bf16* Qb   = (__bf16*)(w + (40ull << 20));
  __bf16* Kb   = (__bf16*)(w + (56ull << 20));
  __bf16* Vb   = (__bf16*)(w + (72ull << 20));
  __bf16* FF   = (__bf16*)(w + (40ull << 20));
  float*  AO   = (float*) (w + (104ull << 20));
  float* out = (float*)d_out;

  const int M = 8192, NTOK = M * DMODEL;
  dim3 blk(256);
  dim3 gC(NTOK / 1024);   // cast
  dim3 gT6(2, 32, 16);    // per-head weight transpose [16][1024][64] -> [16][64][1024]
  dim3 gP(8, 64);         // projection GEMM N=1024
  dim3 gA(16, 128);       // attention
  dim3 gL(M);

  k_cast<<<gC, blk, 0, stream>>>(dec, decB, NTOK);
  k_cast<<<gC, blk, 0, stream>>>(enc, encB, NTOK);

  // ---- masked self-attention ----
  k_transpose<<<gT6, blk, 0, stream>>>(m_wq, WB, 1024, 64);
  k_gemm<false, __bf16><<<gP, blk, 0, stream>>>(decB, WB, m_bq, Qb, M, 1024, 1024);
  k_transpose<<<gT6, blk, 0, stream>>>(m_wk, WB, 1024, 64);
  k_gemm<false, __bf16><<<gP, blk, 0, stream>>>(decB, WB, m_bk, Kb, M, 1024, 1024);
  k_transpose<<<gT6, blk, 0, stream>>>(m_wv, WB, 1024, 64);
  k_gemm<false, __bf16><<<gP, blk, 0, stream>>>(decB, WB, m_bv, Vb, M, 1024, 1024);
  k_attn<true><<<gA, blk, 0, stream>>>(Qb, Kb, Vb, AO, 1024, 1024);
  k_ln_add<float, __bf16><<<gL, blk, 0, stream>>>(dec, AO, ln1_g, ln1_b, X1b);  // decB dead

  // ---- cross-attention ----
  k_transpose<<<gT6, blk, 0, stream>>>(c_wq, WB, 1024, 64);
  k_gemm<false, __bf16><<<gP, blk, 0, stream>>>(X1b, WB, c_bq, Qb, M, 1024, 1024);
  k_transpose<<<gT6, blk, 0, stream>>>(c_wk, WB, 1024, 64);
  k_gemm<false, __bf16><<<gP, blk, 0, stream>>>(encB, WB, c_bk, Kb, M, 1024, 1024);
  k_transpose<<<gT6, blk, 0, stream>>>(c_wv, WB, 1024, 64);
  k_gemm<false, __bf16><<<gP, blk, 0, stream>>>(encB, WB, c_bv, Vb, M, 1024, 1024);
  k_attn<false><<<gA, blk, 0, stream>>>(Qb, Kb, Vb, AO, 1024, 1024);
  k_ln_add<__bf16, __bf16><<<gL, blk, 0, stream>>>(X1b, AO, ln2_g, ln2_b, X2b);  // encB dead

  // ---- FFN (Qb/Kb/Vb dead -> FF overlays [40,104)) ----
  k_transpose<<<dim3(128, 32, 1), blk, 0, stream>>>(ff_w1, WB, 1024, 4096);
  k_gemm<true, __bf16><<<dim3(32, 64), blk, 0, stream>>>(X2b, WB, ff_b1, FF, M, 4096, 1024);
  k_transpose<<<dim3(32, 128, 1), blk, 0, stream>>>(ff_w2, WB, 4096, 1024);
  k_gemm<false, float><<<dim3(8, 64), blk, 0, stream>>>(FF, WB, ff_b2, AO, M, 1024, 4096);
  k_ln_add<__bf16, float><<<gL, blk, 0, stream>>>(X2b, AO, ln2_g, ln2_b, out);
}

// Round 3
// 849.859 us; speedup vs baseline: 1.0839x; 1.0839x over previous
//
#include <hip/hip_runtime.h>
#include <hip/hip_bf16.h>
#include <cstdint>

typedef __bf16 bf16x8 __attribute__((ext_vector_type(8)));
typedef float f32x4 __attribute__((ext_vector_type(4)));

union U128 { uint4 u; __bf16 h[8]; };
union U64  { uint2 u; __bf16 h[4]; };

#define DMODEL 1024
#define NHEAD  16
#define DHEAD  64

__device__ __forceinline__ void async_copy16(const void* g, void* l) {
  __builtin_amdgcn_global_load_lds(
      (const __attribute__((address_space(1))) void*)g,
      (__attribute__((address_space(3))) void*)l, 16, 0, 0);
}

// ---------------- fp32 -> bf16 cast ----------------
__global__ __launch_bounds__(256) void k_cast(const float* __restrict__ s,
    __bf16* __restrict__ d, int n) {
  int i = (blockIdx.x * 256 + threadIdx.x) * 4;
  if (i < n) {
    float4 v = *(const float4*)(s + i);
    U64 o;
    o.h[0] = (__bf16)v.x; o.h[1] = (__bf16)v.y;
    o.h[2] = (__bf16)v.z; o.h[3] = (__bf16)v.w;
    *(uint2*)(d + i) = o.u;
  }
}

// ------------- batched 32x32 transpose + cast: src[z][R][C] f32 -> dst[z][C][R] bf16 -------------
__global__ __launch_bounds__(256) void k_transpose(const float* __restrict__ src,
    __bf16* __restrict__ dst, int R, int C) {
  __shared__ __bf16 tile[32][33];
  src += (size_t)blockIdx.z * R * C;
  dst += (size_t)blockIdx.z * R * C;
  int c0 = blockIdx.x * 32, r0 = blockIdx.y * 32;
  int tx = threadIdx.x & 31, ty = threadIdx.x >> 5;
  for (int i = ty; i < 32; i += 8)
    tile[i][tx] = (__bf16)src[(size_t)(r0 + i) * C + (c0 + tx)];
  __syncthreads();
  for (int i = ty; i < 32; i += 8)
    dst[(size_t)(c0 + i) * R + (r0 + tx)] = tile[tx][i];
}

// ---------------- bf16 TN GEMM (m97 structure): C[M,N] = A[M,K] * Bt[N,K]^T + bias -------------
// 128x128 tile, BK=32, global_load_lds staging into unpadded [128][32] LDS.
template<bool RELU, typename OutT>
__global__ __launch_bounds__(256, 2) void k_gemm(const __bf16* __restrict__ A,
    const __bf16* __restrict__ Bt, const float* __restrict__ bias,
    OutT* __restrict__ C, int M, int N, int K) {
  __shared__ __bf16 As[128][32];   // 64B rows, contiguous in staging-lane order
  __shared__ __bf16 Bs[128][32];
  const int m0 = blockIdx.y * 128, n0 = blockIdx.x * 128;
  const int t = threadIdx.x;
  const int wave = t >> 6, lane = t & 63;
  const int wm = (wave & 1) * 64, wn = (wave >> 1) * 64;
  const int lrow = lane & 15, quad = lane >> 4;
  // staging: wave w covers rows [w*16, w*16+16) (low) and +64 (high); lane i -> row w*16+i/4, col (i&3)*8
  const int r16 = lane >> 2, c8 = (lane & 3) * 8;
  const __bf16* ApL = A  + (size_t)(m0 + wave * 16 + r16) * K + c8;
  const __bf16* ApH = ApL + (size_t)64 * K;
  const __bf16* BpL = Bt + (size_t)(n0 + wave * 16 + r16) * K + c8;
  const __bf16* BpH = BpL + (size_t)64 * K;
  __bf16* ldsAL = &As[wave * 16][0];
  __bf16* ldsAH = &As[wave * 16 + 64][0];
  __bf16* ldsBL = &Bs[wave * 16][0];
  __bf16* ldsBH = &Bs[wave * 16 + 64][0];
  f32x4 acc[4][4] = {};
  for (int k0 = 0; k0 < K; k0 += 32) {
    __syncthreads();            // previous iteration's ds_reads complete
    async_copy16(ApL + k0, ldsAL);
    async_copy16(ApH + k0, ldsAH);
    async_copy16(BpL + k0, ldsBL);
    async_copy16(BpH + k0, ldsBH);
    __syncthreads();            // drains vmcnt -> staged data visible
    bf16x8 af[4], bfv[4];
    for (int i = 0; i < 4; i++) {
      af[i]  = *(const bf16x8*)&As[wm + i * 16 + lrow][quad * 8];
      bfv[i] = *(const bf16x8*)&Bs[wn + i * 16 + lrow][quad * 8];
    }
    for (int mi = 0; mi < 4; mi++)
      for (int ni = 0; ni < 4; ni++)
        acc[mi][ni] = __builtin_amdgcn_mfma_f32_16x16x32_bf16(af[mi], bfv[ni], acc[mi][ni], 0, 0, 0);
  }
  for (int ni = 0; ni < 4; ni++) {
    int col = n0 + wn + ni * 16 + lrow;
    float bv = bias[col];
    for (int mi = 0; mi < 4; mi++) {
      int row = m0 + wm + mi * 16 + quad * 4;
      for (int r = 0; r < 4; r++) {
        float v = acc[mi][ni][r] + bv;
        if (RELU) v = fmaxf(v, 0.f);
        C[(size_t)(row + r) * N + col] = (OutT)v;
      }
    }
  }
}

// ---------------- fused flash-style attention, register-resident softmax ----------------
// grid (Lq/64, B*H); Q/K/V bf16 layout [B, L, H*64]; O fp32 same layout
template<bool CAUSAL>
__global__ __launch_bounds__(256, 4) void k_attn(const __bf16* __restrict__ Q,
    const __bf16* __restrict__ Kg, const __bf16* __restrict__ Vg,
    float* __restrict__ O, int Lq, int Lk) {
  __shared__ alignas(16) __bf16 Qs[64][72];
  __shared__ alignas(16) __bf16 Ks[64][72];
  __shared__ alignas(16) __bf16 Vt[64][72];   // transposed: [vd][k]
  __shared__ alignas(16) __bf16 Ps[64][72];
  const int t = threadIdx.x;
  const int wave = t >> 6, lane = t & 63;
  const int lrow = lane & 15, quad = lane >> 4;
  const int wm16 = wave * 16;
  const int qt = CAUSAL ? (gridDim.x - 1 - blockIdx.x) : blockIdx.x;  // heavy blocks first
  const int q0 = qt * 64;
  const int b = blockIdx.y >> 4, h = blockIdx.y & 15;
  const __bf16* Qb = Q  + (size_t)b * Lq * DMODEL + h * DHEAD;
  const __bf16* Kb = Kg + (size_t)b * Lk * DMODEL + h * DHEAD;
  const __bf16* Vb = Vg + (size_t)b * Lk * DMODEL + h * DHEAD;
  {
    int row = t >> 3, col = (t & 7) * 8;
    *(uint4*)&Qs[row][col]      = *(const uint4*)(Qb + (size_t)(q0 + row) * DMODEL + col);
    *(uint4*)&Qs[row + 32][col] = *(const uint4*)(Qb + (size_t)(q0 + row + 32) * DMODEL + col);
  }
  f32x4 acc_o[4] = {};
  float m_r[4] = {-1e30f, -1e30f, -1e30f, -1e30f};
  float l_r[4] = {};
  const float scale = 0.125f;  // 1/sqrt(64)
  const int nkt = CAUSAL ? (qt + 1) : (Lk / 64);
  const int krow = t >> 3, kcol = (t & 7) * 8;
  const int vkk = t & 63, vd8 = t >> 6;
  for (int kt = 0; kt < nkt; kt++) {
    const int k0 = kt * 64;
    uint4 ka  = *(const uint4*)(Kb + (size_t)(k0 + krow) * DMODEL + kcol);
    uint4 ka2 = *(const uint4*)(Kb + (size_t)(k0 + krow + 32) * DMODEL + kcol);
    uint4 va  = *(const uint4*)(Vb + (size_t)(k0 + vkk) * DMODEL + vd8 * 8);
    uint4 va2 = *(const uint4*)(Vb + (size_t)(k0 + vkk) * DMODEL + (vd8 + 4) * 8);
    __syncthreads();   // all waves done reading prior Ks/Vt
    *(uint4*)&Ks[krow][kcol]      = ka;
    *(uint4*)&Ks[krow + 32][kcol] = ka2;
    { U128 u; u.u = va;  for (int j = 0; j < 8; j++) Vt[vd8 * 8 + j][vkk] = u.h[j]; }
    { U128 u; u.u = va2; for (int j = 0; j < 8; j++) Vt[(vd8 + 4) * 8 + j][vkk] = u.h[j]; }
    __syncthreads();
    // S = Q K^T : wave computes 16 q-rows x 64 k-cols; lane holds rows quad*4+r, col nb*16+lrow
    f32x4 accs[4] = {};
    for (int ks = 0; ks < 2; ks++) {
      bf16x8 qa = *(const bf16x8*)&Qs[wm16 + lrow][ks * 32 + quad * 8];
      for (int nb = 0; nb < 4; nb++) {
        bf16x8 kfr = *(const bf16x8*)&Ks[nb * 16 + lrow][ks * 32 + quad * 8];
        accs[nb] = __builtin_amdgcn_mfma_f32_16x16x32_bf16(qa, kfr, accs[nb], 0, 0, 0);
      }
    }
    // scale + causal mask, per-lane partial row max
    float pm[4] = {-1e30f, -1e30f, -1e30f, -1e30f};
    for (int nb = 0; nb < 4; nb++)
      for (int r = 0; r < 4; r++) {
        float s = accs[nb][r] * scale;
        if (CAUSAL && kt == qt)
          s = ((nb * 16 + lrow) <= (wm16 + quad * 4 + r)) ? s : -1e30f;
        accs[nb][r] = s;
        pm[r] = fmaxf(pm[r], s);
      }
    // row max across the 16 lanes of this quad group
    for (int msk = 1; msk <= 8; msk <<= 1)
      for (int r = 0; r < 4; r++)
        pm[r] = fmaxf(pm[r], __shfl_xor(pm[r], msk));
    // online-softmax update (state replicated across quad's 16 lanes)
    float alpha[4], rs[4];
    for (int r = 0; r < 4; r++) {
      float mn = fmaxf(m_r[r], pm[r]);
      alpha[r] = __expf(m_r[r] - mn);
      m_r[r] = mn;
      float srow = 0.f;
      for (int nb = 0; nb < 4; nb++) {
        float p = __expf(accs[nb][r] - mn);
        accs[nb][r] = p;
        srow += p;
      }
      rs[r] = srow;
    }
    for (int msk = 1; msk <= 8; msk <<= 1)
      for (int r = 0; r < 4; r++)
        rs[r] += __shfl_xor(rs[r], msk);
    for (int r = 0; r < 4; r++)
      l_r[r] = l_r[r] * alpha[r] + rs[r];
    // rescale O accumulators (same C-layout row ownership)
    for (int ni = 0; ni < 4; ni++)
      for (int r = 0; r < 4; r++)
        acc_o[ni][r] *= alpha[r];
    // P -> LDS (C-layout scatter; rows wm16..wm16+15 owned and re-read by THIS wave only)
    for (int nb = 0; nb < 4; nb++)
      for (int r = 0; r < 4; r++)
        Ps[wm16 + quad * 4 + r][nb * 16 + lrow] = (__bf16)accs[nb][r];
    // O += P V   (A-frag from Ps, B-frag from Vt)
    for (int ks = 0; ks < 2; ks++) {
      bf16x8 pa = *(const bf16x8*)&Ps[wm16 + lrow][ks * 32 + quad * 8];
      for (int ni = 0; ni < 4; ni++) {
        bf16x8 vfr = *(const bf16x8*)&Vt[ni * 16 + lrow][ks * 32 + quad * 8];
        acc_o[ni] = __builtin_amdgcn_mfma_f32_16x16x32_bf16(pa, vfr, acc_o[ni], 0, 0, 0);
      }
    }
  }
  float* Ob = O + (size_t)b * Lq * DMODEL + h * DHEAD;
  for (int r = 0; r < 4; r++) {
    float linv = 1.f / fmaxf(l_r[r], 1e-30f);
    int q = wm16 + quad * 4 + r;
    for (int ni = 0; ni < 4; ni++)
      Ob[(size_t)(q0 + q) * DMODEL + ni * 16 + lrow] = acc_o[ni][r] * linv;
  }
}

// ---------------- residual(ResT + fp32) + LayerNorm -> OutT ----------------
template<typename ResT, typename OutT>
__global__ __launch_bounds__(256) void k_ln_add(const ResT* __restrict__ a,
    const float* __restrict__ bres, const float* __restrict__ g,
    const float* __restrict__ be, OutT* __restrict__ out) {
  __shared__ float red[2][4];
  const int r = blockIdx.x, t = threadIdx.x;
  const size_t base = (size_t)r * DMODEL + t * 4;
  float x[4];
  for (int i = 0; i < 4; i++) x[i] = (float)a[base + i] + bres[base + i];
  float s  = x[0] + x[1] + x[2] + x[3];
  float s2 = x[0]*x[0] + x[1]*x[1] + x[2]*x[2] + x[3]*x[3];
  for (int off = 32; off > 0; off >>= 1) {
    s  += __shfl_down(s, off);
    s2 += __shfl_down(s2, off);
  }
  if ((t & 63) == 0) { red[0][t >> 6] = s; red[1][t >> 6] = s2; }
  __syncthreads();
  s  = red[0][0] + red[0][1] + red[0][2] + red[0][3];
  s2 = red[1][0] + red[1][1] + red[1][2] + red[1][3];
  const float mean = s * (1.f / DMODEL);
  const float var  = s2 * (1.f / DMODEL) - mean * mean;
  const float rstd = rsqrtf(var + 1e-5f);
  for (int i = 0; i < 4; i++)
    out[base + i] = (OutT)((x[i] - mean) * rstd * g[t * 4 + i] + be[t * 4 + i]);
}

extern "C" void kernel_launch(void* const* d_in, const int* in_sizes, int n_in,
                              void* d_out, int out_size, void* d_ws, size_t ws_size,
                              hipStream_t stream) {
  (void)in_sizes; (void)n_in; (void)out_size; (void)ws_size;
  const float* dec   = (const float*)d_in[0];
  const float* enc   = (const float*)d_in[1];
  const float* m_wq  = (const float*)d_in[2];
  const float* m_bq  = (const float*)d_in[3];
  const float* m_wk  = (const float*)d_in[4];
  const float* m_bk  = (const float*)d_in[5];
  const float* m_wv  = (const float*)d_in[6];
  const float* m_bv  = (const float*)d_in[7];
  const float* c_wq  = (const float*)d_in[8];
  const float* c_bq  = (const float*)d_in[9];
  const float* c_wk  = (const float*)d_in[10];
  const float* c_bk  = (const float*)d_in[11];
  const float* c_wv  = (const float*)d_in[12];
  const float* c_bv  = (const float*)d_in[13];
  const float* ff_w1 = (const float*)d_in[14];
  const float* ff_b1 = (const float*)d_in[15];
  const float* ff_w2 = (const float*)d_in[16];
  const float* ff_b2 = (const float*)d_in[17];
  const float* ln1_g = (const float*)d_in[18];
  const float* ln1_b = (const float*)d_in[19];
  const float* ln2_g = (const float*)d_in[20];
  const float* ln2_b = (const float*)d_in[21];

  // workspace layout (peak 136 MB), sequential reuse:
  //  [0,16) decB->X1b | [16,32) encB->X2b | [32,40) WB | [40,56) Qb | [56,72) Kb | [72,88) Vb
  //  [40,104) FF (FFN phase) | [104,136) AO (fp32)
  char* w = (char*)d_ws;
  __bf16* decB = (__bf16*)(w);
  __bf16* encB = (__bf16*)(w + (16ull << 20));
  __bf16* X1b  = decB;
  __bf16* X2b  = encB;
  __bf16* WB   = (__bf16*)(w + (32ull << 20));
  __bf16* Qb   = (__bf16*)(w + (40ull << 20));
  __bf16* Kb   = (__bf16*)(w + (56ull << 20));
  __bf16* Vb   = (__bf16*)(w + (72ull << 20));
  __bf16* FF   = (__bf16*)(w + (40ull << 20));
  float*  AO   = (float*) (w + (104ull << 20));
  float* out = (float*)d_out;

  const int M = 8192, NTOK = M * DMODEL;
  dim3 blk(256);
  dim3 gC(NTOK / 1024);   // cast
  dim3 gT6(2, 32, 16);    // per-head weight transpose [16][1024][64] -> [16][64][1024]
  dim3 gP(8, 64);         // projection GEMM N=1024
  dim3 gA(16, 128);       // attention
  dim3 gL(M);

  k_cast<<<gC, blk, 0, stream>>>(dec, decB, NTOK);
  k_cast<<<gC, blk, 0, stream>>>(enc, encB, NTOK);

  // ---- masked self-attention ----
  k_transpose<<<gT6, blk, 0, stream>>>(m_wq, WB, 1024, 64);
  k_gemm<false, __bf16><<<gP, blk, 0, stream>>>(decB, WB, m_bq, Qb, M, 1024, 1024);
  k_transpose<<<gT6, blk, 0, stream>>>(m_wk, WB, 1024, 64);
  k_gemm<false, __bf16><<<gP, blk, 0, stream>>>(decB, WB, m_bk, Kb, M, 1024, 1024);
  k_transpose<<<gT6, blk, 0, stream>>>(m_wv, WB, 1024, 64);
  k_gemm<false, __bf16><<<gP, blk, 0, stream>>>(decB, WB, m_bv, Vb, M, 1024, 1024);
  k_attn<true><<<gA, blk, 0, stream>>>(Qb, Kb, Vb, AO, 1024, 1024);
  k_ln_add<float, __bf16><<<gL, blk, 0, stream>>>(dec, AO, ln1_g, ln1_b, X1b);  // decB dead

  // ---- cross-attention ----
  k_transpose<<<gT6, blk, 0, stream>>>(c_wq, WB, 1024, 64);
  k_gemm<false, __bf16><<<gP, blk, 0, stream>>>(X1b, WB, c_bq, Qb, M, 1024, 1024);
  k_transpose<<<gT6, blk, 0, stream>>>(c_wk, WB, 1024, 64);
  k_gemm<false, __bf16><<<gP, blk, 0, stream>>>(encB, WB, c_bk, Kb, M, 1024, 1024);
  k_transpose<<<gT6, blk, 0, stream>>>(c_wv, WB, 1024, 64);
  k_gemm<false, __bf16><<<gP, blk, 0, stream>>>(encB, WB, c_bv, Vb, M, 1024, 1024);
  k_attn<false><<<gA, blk, 0, stream>>>(Qb, Kb, Vb, AO, 1024, 1024);
  k_ln_add<__bf16, __bf16><<<gL, blk, 0, stream>>>(X1b, AO, ln2_g, ln2_b, X2b);  // encB dead

  // ---- FFN (Qb/Kb/Vb dead -> FF overlays [40,104)) ----
  k_transpose<<<dim3(128, 32, 1), blk, 0, stream>>>(ff_w1, WB, 1024, 4096);
  k_gemm<true, __bf16><<<dim3(32, 64), blk, 0, stream>>>(X2b, WB, ff_b1, FF, M, 4096, 1024);
  k_transpose<<<dim3(32, 128, 1), blk, 0, stream>>>(ff_w2, WB, 4096, 1024);
  k_gemm<false, float><<<dim3(8, 64), blk, 0, stream>>>(FF, WB, ff_b2, AO, M, 1024, 4096);
  k_ln_add<__bf16, float><<<gL, blk, 0, stream>>>(X2b, AO, ln2_g, ln2_b, out);
}

// Round 4
// 804.330 us; speedup vs baseline: 1.1453x; 1.0566x over previous
//
#include <hip/hip_runtime.h>
#include <hip/hip_bf16.h>
#include <cstdint>

typedef __bf16 bf16x8 __attribute__((ext_vector_type(8)));
typedef float f32x4 __attribute__((ext_vector_type(4)));

union U128 { uint4 u; __bf16 h[8]; };
union U64  { uint2 u; __bf16 h[4]; };

#define DMODEL 1024
#define NHEAD  16
#define DHEAD  64

__device__ __forceinline__ void async_copy16(const void* g, void* l) {
  __builtin_amdgcn_global_load_lds(
      (const __attribute__((address_space(1))) void*)g,
      (__attribute__((address_space(3))) void*)l, 16, 0, 0);
}

// ---------------- fp32 -> bf16 cast ----------------
__global__ __launch_bounds__(256) void k_cast(const float* __restrict__ s,
    __bf16* __restrict__ d, int n) {
  int i = (blockIdx.x * 256 + threadIdx.x) * 4;
  if (i < n) {
    float4 v = *(const float4*)(s + i);
    U64 o;
    o.h[0] = (__bf16)v.x; o.h[1] = (__bf16)v.y;
    o.h[2] = (__bf16)v.z; o.h[3] = (__bf16)v.w;
    *(uint2*)(d + i) = o.u;
  }
}

// ---------------- pack up to 3 fp32 bias vectors (n each) into dst ----------------
__global__ __launch_bounds__(256) void k_pack(float* __restrict__ dst,
    const float* __restrict__ s0, const float* __restrict__ s1,
    const float* __restrict__ s2, int n) {
  int i = blockIdx.x * 256 + threadIdx.x;
  if (i < n) dst[i] = s0[i];
  else if (i < 2 * n) dst[i] = s1[i - n];
  else if (i < 3 * n) dst[i] = s2[i - 2 * n];
}

// ------------- batched 32x32 transpose + cast: src[z][R][C] f32 -> dst[z][C][R] bf16 -------------
__global__ __launch_bounds__(256) void k_transpose(const float* __restrict__ src,
    __bf16* __restrict__ dst, int R, int C) {
  __shared__ __bf16 tile[32][33];
  src += (size_t)blockIdx.z * R * C;
  dst += (size_t)blockIdx.z * R * C;
  int c0 = blockIdx.x * 32, r0 = blockIdx.y * 32;
  int tx = threadIdx.x & 31, ty = threadIdx.x >> 5;
  for (int i = ty; i < 32; i += 8)
    tile[i][tx] = (__bf16)src[(size_t)(r0 + i) * C + (c0 + tx)];
  __syncthreads();
  for (int i = ty; i < 32; i += 8)
    dst[(size_t)(c0 + i) * R + (r0 + tx)] = tile[tx][i];
}

// ---------------- bf16 TN GEMM: C[M,N] = A[M,K] * Bt[N,K]^T + bias ----------------
// 128x128 tile, BK=64 (32 MFMA per barrier pair), global_load_lds staging into
// unpadded [128][64] LDS with 16B-granule XOR swizzle (granule ^= row&7) so
// ds_read_b128 stays min-conflict despite 128B (bank-aligned) rows.
template<bool RELU, typename OutT>
__global__ __launch_bounds__(256, 3) void k_gemm(const __bf16* __restrict__ A,
    const __bf16* __restrict__ Bt, const float* __restrict__ bias,
    OutT* __restrict__ C, int M, int N, int K) {
  __shared__ __bf16 As[128][64];
  __shared__ __bf16 Bs[128][64];
  const int m0 = blockIdx.y * 128, n0 = blockIdx.x * 128;
  const int t = threadIdx.x;
  const int wave = t >> 6, lane = t & 63;
  const int wm = (wave & 1) * 64, wn = (wave >> 1) * 64;
  const int lrow = lane & 15, quad = lane >> 4;
  // staging: copy j stages rows [wave*8 + j*32, +8); lane -> row base+lane/8,
  // global 16B-granule (lane&7) ^ ((lane>>3)&7)  (the XOR swizzle)
  const int r8 = lane >> 3;
  const int gG = (lane & 7) ^ (r8 & 7);
  const __bf16* Ap[4]; const __bf16* Bp[4];
  __bf16* lA[4]; __bf16* lB[4];
  for (int j = 0; j < 4; j++) {
    int rr = wave * 8 + j * 32 + r8;
    Ap[j] = A  + (size_t)(m0 + rr) * K + gG * 8;
    Bp[j] = Bt + (size_t)(n0 + rr) * K + gG * 8;
    lA[j] = &As[wave * 8 + j * 32][0];
    lB[j] = &Bs[wave * 8 + j * 32][0];
  }
  f32x4 acc[4][4] = {};
  for (int k0 = 0; k0 < K; k0 += 64) {
    __syncthreads();            // previous iteration's ds_reads complete
    for (int j = 0; j < 4; j++) {
      async_copy16(Ap[j] + k0, lA[j]);
      async_copy16(Bp[j] + k0, lB[j]);
    }
    __syncthreads();            // drains vmcnt -> staged data visible
    for (int ks = 0; ks < 2; ks++) {
      bf16x8 af[4], bfv[4];
      for (int i = 0; i < 4; i++) {
        int ra = wm + i * 16 + lrow, rb = wn + i * 16 + lrow;
        af[i]  = *(const bf16x8*)&As[ra][(((ks * 4 + quad) ^ (ra & 7))) * 8];
        bfv[i] = *(const bf16x8*)&Bs[rb][(((ks * 4 + quad) ^ (rb & 7))) * 8];
      }
      for (int mi = 0; mi < 4; mi++)
        for (int ni = 0; ni < 4; ni++)
          acc[mi][ni] = __builtin_amdgcn_mfma_f32_16x16x32_bf16(af[mi], bfv[ni], acc[mi][ni], 0, 0, 0);
    }
  }
  for (int ni = 0; ni < 4; ni++) {
    int col = n0 + wn + ni * 16 + lrow;
    float bv = bias[col];
    for (int mi = 0; mi < 4; mi++) {
      int row = m0 + wm + mi * 16 + quad * 4;
      for (int r = 0; r < 4; r++) {
        float v = acc[mi][ni][r] + bv;
        if (RELU) v = fmaxf(v, 0.f);
        C[(size_t)(row + r) * N + col] = (OutT)v;
      }
    }
  }
}

// ---------------- fused flash-style attention, register-resident softmax ----------------
// grid (Lq/64, B*H); Q rows stride qs, K/V rows stride kvs (elements); O fp32 [B,L,1024]
template<bool CAUSAL>
__global__ __launch_bounds__(256, 4) void k_attn(const __bf16* __restrict__ Q,
    const __bf16* __restrict__ Kg, const __bf16* __restrict__ Vg,
    float* __restrict__ O, int Lq, int Lk, int qs, int kvs) {
  __shared__ alignas(16) __bf16 Qs[64][72];
  __shared__ alignas(16) __bf16 Ks[64][72];
  __shared__ alignas(16) __bf16 Vt[64][72];   // transposed: [vd][k]
  __shared__ alignas(16) __bf16 Ps[64][72];
  const int t = threadIdx.x;
  const int wave = t >> 6, lane = t & 63;
  const int lrow = lane & 15, quad = lane >> 4;
  const int wm16 = wave * 16;
  const int qt = CAUSAL ? (gridDim.x - 1 - blockIdx.x) : blockIdx.x;  // heavy blocks first
  const int q0 = qt * 64;
  const int b = blockIdx.y >> 4, h = blockIdx.y & 15;
  const __bf16* Qb = Q  + (size_t)b * Lq * qs  + h * DHEAD;
  const __bf16* Kb = Kg + (size_t)b * Lk * kvs + h * DHEAD;
  const __bf16* Vb = Vg + (size_t)b * Lk * kvs + h * DHEAD;
  {
    // stage Q with softmax scale folded in (exact: *0.125 = exponent-3)
    int row = t >> 3, col = (t & 7) * 8;
    U128 u0, u1;
    u0.u = *(const uint4*)(Qb + (size_t)(q0 + row) * qs + col);
    u1.u = *(const uint4*)(Qb + (size_t)(q0 + row + 32) * qs + col);
    for (int j = 0; j < 8; j++) {
      u0.h[j] = (__bf16)((float)u0.h[j] * 0.125f);
      u1.h[j] = (__bf16)((float)u1.h[j] * 0.125f);
    }
    *(uint4*)&Qs[row][col]      = u0.u;
    *(uint4*)&Qs[row + 32][col] = u1.u;
  }
  f32x4 acc_o[4] = {};
  float m_r[4] = {-1e30f, -1e30f, -1e30f, -1e30f};
  float l_r[4] = {};
  const int nkt = CAUSAL ? (qt + 1) : (Lk / 64);
  const int krow = t >> 3, kcol = (t & 7) * 8;
  const int vkk = t & 63, vd8 = t >> 6;
  for (int kt = 0; kt < nkt; kt++) {
    const int k0 = kt * 64;
    uint4 ka  = *(const uint4*)(Kb + (size_t)(k0 + krow) * kvs + kcol);
    uint4 ka2 = *(const uint4*)(Kb + (size_t)(k0 + krow + 32) * kvs + kcol);
    uint4 va  = *(const uint4*)(Vb + (size_t)(k0 + vkk) * kvs + vd8 * 8);
    uint4 va2 = *(const uint4*)(Vb + (size_t)(k0 + vkk) * kvs + (vd8 + 4) * 8);
    __syncthreads();   // all waves done reading prior Ks/Vt
    *(uint4*)&Ks[krow][kcol]      = ka;
    *(uint4*)&Ks[krow + 32][kcol] = ka2;
    { U128 u; u.u = va;  for (int j = 0; j < 8; j++) Vt[vd8 * 8 + j][vkk] = u.h[j]; }
    { U128 u; u.u = va2; for (int j = 0; j < 8; j++) Vt[(vd8 + 4) * 8 + j][vkk] = u.h[j]; }
    __syncthreads();
    // S = Q K^T : lane holds rows wm16+quad*4+r, col nb*16+lrow (scale pre-folded)
    f32x4 accs[4] = {};
    for (int ks = 0; ks < 2; ks++) {
      bf16x8 qa = *(const bf16x8*)&Qs[wm16 + lrow][ks * 32 + quad * 8];
      for (int nb = 0; nb < 4; nb++) {
        bf16x8 kfr = *(const bf16x8*)&Ks[nb * 16 + lrow][ks * 32 + quad * 8];
        accs[nb] = __builtin_amdgcn_mfma_f32_16x16x32_bf16(qa, kfr, accs[nb], 0, 0, 0);
      }
    }
    // causal mask + per-lane partial row max
    float pm[4] = {-1e30f, -1e30f, -1e30f, -1e30f};
    for (int nb = 0; nb < 4; nb++)
      for (int r = 0; r < 4; r++) {
        float s = accs[nb][r];
        if (CAUSAL && kt == qt)
          s = ((nb * 16 + lrow) <= (wm16 + quad * 4 + r)) ? s : -1e30f;
        accs[nb][r] = s;
        pm[r] = fmaxf(pm[r], s);
      }
    for (int msk = 1; msk <= 8; msk <<= 1)
      for (int r = 0; r < 4; r++)
        pm[r] = fmaxf(pm[r], __shfl_xor(pm[r], msk));
    float alpha[4], rs[4];
    for (int r = 0; r < 4; r++) {
      float mn = fmaxf(m_r[r], pm[r]);
      alpha[r] = __expf(m_r[r] - mn);
      m_r[r] = mn;
      float srow = 0.f;
      for (int nb = 0; nb < 4; nb++) {
        float p = __expf(accs[nb][r] - mn);
        accs[nb][r] = p;
        srow += p;
      }
      rs[r] = srow;
    }
    for (int msk = 1; msk <= 8; msk <<= 1)
      for (int r = 0; r < 4; r++)
        rs[r] += __shfl_xor(rs[r], msk);
    for (int r = 0; r < 4; r++)
      l_r[r] = l_r[r] * alpha[r] + rs[r];
    for (int ni = 0; ni < 4; ni++)
      for (int r = 0; r < 4; r++)
        acc_o[ni][r] *= alpha[r];
    // P -> LDS (rows wm16..+15 owned and re-read by THIS wave only)
    for (int nb = 0; nb < 4; nb++)
      for (int r = 0; r < 4; r++)
        Ps[wm16 + quad * 4 + r][nb * 16 + lrow] = (__bf16)accs[nb][r];
    // O += P V
    for (int ks = 0; ks < 2; ks++) {
      bf16x8 pa = *(const bf16x8*)&Ps[wm16 + lrow][ks * 32 + quad * 8];
      for (int ni = 0; ni < 4; ni++) {
        bf16x8 vfr = *(const bf16x8*)&Vt[ni * 16 + lrow][ks * 32 + quad * 8];
        acc_o[ni] = __builtin_amdgcn_mfma_f32_16x16x32_bf16(pa, vfr, acc_o[ni], 0, 0, 0);
      }
    }
  }
  float* Ob = O + (size_t)b * Lq * DMODEL + h * DHEAD;
  for (int r = 0; r < 4; r++) {
    float linv = 1.f / fmaxf(l_r[r], 1e-30f);
    int q = wm16 + quad * 4 + r;
    for (int ni = 0; ni < 4; ni++)
      Ob[(size_t)(q0 + q) * DMODEL + ni * 16 + lrow] = acc_o[ni][r] * linv;
  }
}

// ---------------- residual(ResT + fp32) + LayerNorm -> OutT ----------------
template<typename ResT, typename OutT>
__global__ __launch_bounds__(256) void k_ln_add(const ResT* __restrict__ a,
    const float* __restrict__ bres, const float* __restrict__ g,
    const float* __restrict__ be, OutT* __restrict__ out) {
  __shared__ float red[2][4];
  const int r = blockIdx.x, t = threadIdx.x;
  const size_t base = (size_t)r * DMODEL + t * 4;
  float x[4];
  for (int i = 0; i < 4; i++) x[i] = (float)a[base + i] + bres[base + i];
  float s  = x[0] + x[1] + x[2] + x[3];
  float s2 = x[0]*x[0] + x[1]*x[1] + x[2]*x[2] + x[3]*x[3];
  for (int off = 32; off > 0; off >>= 1) {
    s  += __shfl_down(s, off);
    s2 += __shfl_down(s2, off);
  }
  if ((t & 63) == 0) { red[0][t >> 6] = s; red[1][t >> 6] = s2; }
  __syncthreads();
  s  = red[0][0] + red[0][1] + red[0][2] + red[0][3];
  s2 = red[1][0] + red[1][1] + red[1][2] + red[1][3];
  const float mean = s * (1.f / DMODEL);
  const float var  = s2 * (1.f / DMODEL) - mean * mean;
  const float rstd = rsqrtf(var + 1e-5f);
  for (int i = 0; i < 4; i++)
    out[base + i] = (OutT)((x[i] - mean) * rstd * g[t * 4 + i] + be[t * 4 + i]);
}

extern "C" void kernel_launch(void* const* d_in, const int* in_sizes, int n_in,
                              void* d_out, int out_size, void* d_ws, size_t ws_size,
                              hipStream_t stream) {
  (void)in_sizes; (void)n_in; (void)out_size; (void)ws_size;
  const float* dec   = (const float*)d_in[0];
  const float* enc   = (const float*)d_in[1];
  const float* m_wq  = (const float*)d_in[2];
  const float* m_bq  = (const float*)d_in[3];
  const float* m_wk  = (const float*)d_in[4];
  const float* m_bk  = (const float*)d_in[5];
  const float* m_wv  = (const float*)d_in[6];
  const float* m_bv  = (const float*)d_in[7];
  const float* c_wq  = (const float*)d_in[8];
  const float* c_bq  = (const float*)d_in[9];
  const float* c_wk  = (const float*)d_in[10];
  const float* c_bk  = (const float*)d_in[11];
  const float* c_wv  = (const float*)d_in[12];
  const float* c_bv  = (const float*)d_in[13];
  const float* ff_w1 = (const float*)d_in[14];
  const float* ff_b1 = (const float*)d_in[15];
  const float* ff_w2 = (const float*)d_in[16];
  const float* ff_b2 = (const float*)d_in[17];
  const float* ln1_g = (const float*)d_in[18];
  const float* ln1_b = (const float*)d_in[19];
  const float* ln2_g = (const float*)d_in[20];
  const float* ln2_b = (const float*)d_in[21];

  // workspace (136 MB):
  //  [0,16)   decB -> X1b          [16,32)  encB -> X2b
  //  [32,40)  WB weights (bf16); fp32 bias pack at +38MB
  //  [40,88)  QKV (self) | [40,72) KV (cross) + [72,88) Qc | [40,104) FF
  //  [104,136) AO (fp32)
  char* w = (char*)d_ws;
  __bf16* decB = (__bf16*)(w);
  __bf16* encB = (__bf16*)(w + (16ull << 20));
  __bf16* X1b  = decB;
  __bf16* X2b  = encB;
  __bf16* WB   = (__bf16*)(w + (32ull << 20));
  float*  BP   = (float*) (w + (38ull << 20));
  __bf16* QKV  = (__bf16*)(w + (40ull << 20));
  __bf16* KV   = (__bf16*)(w + (40ull << 20));
  __bf16* Qc   = (__bf16*)(w + (72ull << 20));
  __bf16* FF   = (__bf16*)(w + (40ull << 20));
  float*  AO   = (float*) (w + (104ull << 20));
  float* out = (float*)d_out;

  const int M = 8192, NTOK = M * DMODEL;
  dim3 blk(256);
  dim3 gC(NTOK / 1024);
  dim3 gT6(2, 32, 16);    // per-head weight transpose [16][1024][64] -> [16][64][1024]
  dim3 gA(16, 128);
  dim3 gL(M);

  k_cast<<<gC, blk, 0, stream>>>(dec, decB, NTOK);
  k_cast<<<gC, blk, 0, stream>>>(enc, encB, NTOK);

  // ---- masked self-attention: fused QKV projection (N=3072) ----
  k_transpose<<<gT6, blk, 0, stream>>>(m_wq, WB, 1024, 64);
  k_transpose<<<gT6, blk, 0, stream>>>(m_wk, WB + (1 << 20), 1024, 64);
  k_transpose<<<gT6, blk, 0, stream>>>(m_wv, WB + (2 << 20), 1024, 64);
  k_pack<<<dim3(12), blk, 0, stream>>>(BP, m_bq, m_bk, m_bv, 1024);
  k_gemm<false, __bf16><<<dim3(24, 64), blk, 0, stream>>>(decB, WB, BP, QKV, M, 3072, 1024);
  k_attn<true><<<gA, blk, 0, stream>>>(QKV, QKV + 1024, QKV + 2048, AO, 1024, 1024, 3072, 3072);
  k_ln_add<float, __bf16><<<gL, blk, 0, stream>>>(dec, AO, ln1_g, ln1_b, X1b);  // decB dead

  // ---- cross-attention: fused KV (N=2048, enc) + Q (X1b) ----
  k_transpose<<<gT6, blk, 0, stream>>>(c_wk, WB, 1024, 64);
  k_transpose<<<gT6, blk, 0, stream>>>(c_wv, WB + (1 << 20), 1024, 64);
  k_transpose<<<gT6, blk, 0, stream>>>(c_wq, WB + (2 << 20), 1024, 64);
  k_pack<<<dim3(8), blk, 0, stream>>>(BP, c_bk, c_bv, c_bv, 1024);
  k_gemm<false, __bf16><<<dim3(16, 64), blk, 0, stream>>>(encB, WB, BP, KV, M, 2048, 1024);
  k_gemm<false, __bf16><<<dim3(8, 64), blk, 0, stream>>>(X1b, WB + (2 << 20), c_bq, Qc, M, 1024, 1024);
  k_attn<false><<<gA, blk, 0, stream>>>(Qc, KV, KV + 1024, AO, 1024, 1024, 1024, 2048);
  k_ln_add<__bf16, __bf16><<<gL, blk, 0, stream>>>(X1b, AO, ln2_g, ln2_b, X2b);  // encB dead

  // ---- FFN (QKV/KV/Qc dead -> FF overlays [40,104)) ----
  k_transpose<<<dim3(128, 32, 1), blk, 0, stream>>>(ff_w1, WB, 1024, 4096);
  k_gemm<true, __bf16><<<dim3(32, 64), blk, 0, stream>>>(X2b, WB, ff_b1, FF, M, 4096, 1024);
  k_transpose<<<dim3(32, 128, 1), blk, 0, stream>>>(ff_w2, WB, 4096, 1024);
  k_gemm<false, float><<<dim3(8, 64), blk, 0, stream>>>(FF, WB, ff_b2, AO, M, 1024, 4096);
  k_ln_add<__bf16, float><<<gL, blk, 0, stream>>>(X2b, AO, ln2_g, ln2_b, out);
}

// Round 5
// 719.286 us; speedup vs baseline: 1.2807x; 1.1182x over previous
//
#include <hip/hip_runtime.h>
#include <hip/hip_bf16.h>
#include <cstdint>

typedef __bf16 bf16x8 __attribute__((ext_vector_type(8)));
typedef __bf16 bf16x4 __attribute__((ext_vector_type(4)));
typedef short  short4v __attribute__((ext_vector_type(4)));
typedef _Float16 f16x4 __attribute__((ext_vector_type(4)));
typedef float f32x4 __attribute__((ext_vector_type(4)));

union U128 { uint4 u; __bf16 h[8]; };
union U64  { uint2 u; __bf16 h[4]; };
union PV4  { uint2 u; bf16x4 b; short4v s; f16x4 f; };

#define DMODEL 1024
#define NHEAD  16
#define DHEAD  64

// ---- 16x16x16 MFMA selection for the PV step (P/V as 4x16-bit per lane) ----
#if __has_builtin(__builtin_amdgcn_mfma_f32_16x16x16_bf16)
#define PV_F16 0
__device__ __forceinline__ f32x4 mfma16(PV4 a, PV4 b, f32x4 c) {
  return __builtin_amdgcn_mfma_f32_16x16x16_bf16(a.b, b.b, c, 0, 0, 0);
}
#elif __has_builtin(__builtin_amdgcn_mfma_f32_16x16x16bf16_1k)
#define PV_F16 0
__device__ __forceinline__ f32x4 mfma16(PV4 a, PV4 b, f32x4 c) {
  return __builtin_amdgcn_mfma_f32_16x16x16bf16_1k(a.s, b.s, c, 0, 0, 0);
}
#else
#define PV_F16 1
__device__ __forceinline__ f32x4 mfma16(PV4 a, PV4 b, f32x4 c) {
  return __builtin_amdgcn_mfma_f32_16x16x16f16(a.f, b.f, c, 0, 0, 0);
}
#endif

__device__ __forceinline__ uint16_t pv_bits(__bf16 v) {
#if PV_F16
  union { _Float16 f; uint16_t u; } x; x.f = (_Float16)(float)v; return x.u;
#else
  union { __bf16 b; uint16_t u; } x; x.b = v; return x.u;
#endif
}

__device__ __forceinline__ PV4 pack4(float a, float b, float c, float d) {
  PV4 r;
#if PV_F16
  r.f = (f16x4){(_Float16)a, (_Float16)b, (_Float16)c, (_Float16)d};
#else
  r.b = (bf16x4){(__bf16)a, (__bf16)b, (__bf16)c, (__bf16)d};
#endif
  return r;
}

__device__ __forceinline__ void async_copy16(const void* g, void* l) {
  __builtin_amdgcn_global_load_lds(
      (const __attribute__((address_space(1))) void*)g,
      (__attribute__((address_space(3))) void*)l, 16, 0, 0);
}

// ---------------- fp32 -> bf16 cast ----------------
__global__ __launch_bounds__(256) void k_cast(const float* __restrict__ s,
    __bf16* __restrict__ d, int n) {
  int i = (blockIdx.x * 256 + threadIdx.x) * 4;
  if (i < n) {
    float4 v = *(const float4*)(s + i);
    U64 o;
    o.h[0] = (__bf16)v.x; o.h[1] = (__bf16)v.y;
    o.h[2] = (__bf16)v.z; o.h[3] = (__bf16)v.w;
    *(uint2*)(d + i) = o.u;
  }
}

// ---------------- pack up to 3 fp32 bias vectors (n each) into dst ----------------
__global__ __launch_bounds__(256) void k_pack(float* __restrict__ dst,
    const float* __restrict__ s0, const float* __restrict__ s1,
    const float* __restrict__ s2, int n) {
  int i = blockIdx.x * 256 + threadIdx.x;
  if (i < n) dst[i] = s0[i];
  else if (i < 2 * n) dst[i] = s1[i - n];
  else if (i < 3 * n) dst[i] = s2[i - 2 * n];
}

// ------------- batched 32x32 transpose + cast: src[z][R][C] f32 -> dst[z][C][R] bf16 -------------
__global__ __launch_bounds__(256) void k_transpose(const float* __restrict__ src,
    __bf16* __restrict__ dst, int R, int C) {
  __shared__ __bf16 tile[32][33];
  src += (size_t)blockIdx.z * R * C;
  dst += (size_t)blockIdx.z * R * C;
  int c0 = blockIdx.x * 32, r0 = blockIdx.y * 32;
  int tx = threadIdx.x & 31, ty = threadIdx.x >> 5;
  for (int i = ty; i < 32; i += 8)
    tile[i][tx] = (__bf16)src[(size_t)(r0 + i) * C + (c0 + tx)];
  __syncthreads();
  for (int i = ty; i < 32; i += 8)
    dst[(size_t)(c0 + i) * R + (r0 + tx)] = tile[tx][i];
}

// ---------------- bf16 TN GEMM: C[M,N] = A[M,K] * Bt[N,K]^T + bias ----------------
// 128x128 tile, BK=64, global_load_lds staging, 16B-granule XOR swizzle.
template<bool RELU, typename OutT>
__global__ __launch_bounds__(256, 3) void k_gemm(const __bf16* __restrict__ A,
    const __bf16* __restrict__ Bt, const float* __restrict__ bias,
    OutT* __restrict__ C, int M, int N, int K) {
  __shared__ __bf16 As[128][64];
  __shared__ __bf16 Bs[128][64];
  const int m0 = blockIdx.y * 128, n0 = blockIdx.x * 128;
  const int t = threadIdx.x;
  const int wave = t >> 6, lane = t & 63;
  const int wm = (wave & 1) * 64, wn = (wave >> 1) * 64;
  const int lrow = lane & 15, quad = lane >> 4;
  const int r8 = lane >> 3;
  const int gG = (lane & 7) ^ (r8 & 7);
  const __bf16* Ap[4]; const __bf16* Bp[4];
  __bf16* lA[4]; __bf16* lB[4];
  for (int j = 0; j < 4; j++) {
    int rr = wave * 8 + j * 32 + r8;
    Ap[j] = A  + (size_t)(m0 + rr) * K + gG * 8;
    Bp[j] = Bt + (size_t)(n0 + rr) * K + gG * 8;
    lA[j] = &As[wave * 8 + j * 32][0];
    lB[j] = &Bs[wave * 8 + j * 32][0];
  }
  f32x4 acc[4][4] = {};
  for (int k0 = 0; k0 < K; k0 += 64) {
    __syncthreads();
    for (int j = 0; j < 4; j++) {
      async_copy16(Ap[j] + k0, lA[j]);
      async_copy16(Bp[j] + k0, lB[j]);
    }
    __syncthreads();
    for (int ks = 0; ks < 2; ks++) {
      bf16x8 af[4], bfv[4];
      for (int i = 0; i < 4; i++) {
        int ra = wm + i * 16 + lrow, rb = wn + i * 16 + lrow;
        af[i]  = *(const bf16x8*)&As[ra][(((ks * 4 + quad) ^ (ra & 7))) * 8];
        bfv[i] = *(const bf16x8*)&Bs[rb][(((ks * 4 + quad) ^ (rb & 7))) * 8];
      }
      for (int mi = 0; mi < 4; mi++)
        for (int ni = 0; ni < 4; ni++)
          acc[mi][ni] = __builtin_amdgcn_mfma_f32_16x16x32_bf16(af[mi], bfv[ni], acc[mi][ni], 0, 0, 0);
    }
  }
  for (int ni = 0; ni < 4; ni++) {
    int col = n0 + wn + ni * 16 + lrow;
    float bv = bias[col];
    for (int mi = 0; mi < 4; mi++) {
      int row = m0 + wm + mi * 16 + quad * 4;
      for (int r = 0; r < 4; r++) {
        float v = acc[mi][ni][r] + bv;
        if (RELU) v = fmaxf(v, 0.f);
        C[(size_t)(row + r) * N + col] = (OutT)v;
      }
    }
  }
}

// ---------------- fused flash attention v2: S^T trick + register PV + 1-barrier pipeline --------
// grid (Lq/64, B*H); Q rows stride qs, K/V rows stride kvs; O fp32 [B,L,1024].
// Each wave: 16 q-rows (q=wm16+lrow), full 64-k tile. S^T = K·Q^T so softmax state is
// per-lane (q=lrow) and P fragments feed mfma16 directly from registers (no LDS round-trip).
template<bool CAUSAL>
__global__ __launch_bounds__(256, 4) void k_attn(const __bf16* __restrict__ Q,
    const __bf16* __restrict__ Kg, const __bf16* __restrict__ Vg,
    float* __restrict__ O, int Lq, int Lk, int qs, int kvs) {
  __shared__ alignas(16) __bf16   Ks[2][64][72];
  __shared__ alignas(16) uint16_t Vt[2][64][72];   // [vd][k], bf16 or f16 bits
  const int t = threadIdx.x;
  const int wave = t >> 6, lane = t & 63;
  const int lrow = lane & 15, quad = lane >> 4;
  const int wm16 = wave * 16;
  const int qt = CAUSAL ? (gridDim.x - 1 - blockIdx.x) : blockIdx.x;  // heavy blocks first
  const int q0 = qt * 64;
  const int b = blockIdx.y >> 4, h = blockIdx.y & 15;
  const __bf16* Qb = Q  + (size_t)b * Lq * qs  + h * DHEAD;
  const __bf16* Kb = Kg + (size_t)b * Lk * kvs + h * DHEAD;
  const __bf16* Vb = Vg + (size_t)b * Lk * kvs + h * DHEAD;
  // preload Q B-fragments (q=wm16+lrow, d=ks*32+quad*8+j), softmax scale folded (exact *0.125)
  bf16x8 qf[2];
  for (int ks = 0; ks < 2; ks++) {
    U128 u;
    u.u = *(const uint4*)(Qb + (size_t)(q0 + wm16 + lrow) * qs + ks * 32 + quad * 8);
    for (int j = 0; j < 8; j++) u.h[j] = (__bf16)((float)u.h[j] * 0.125f);
    qf[ks] = *(const bf16x8*)u.h;
  }
  const int nkt = CAUSAL ? (qt + 1) : (Lk / 64);
  const int krow = t >> 3, kcol = (t & 7) * 8;
  const int vkk = t & 63;
  f32x4 acc_o[4] = {};          // O^T: row vd=ni*16+quad*4+r, col q=lrow
  float m_r = -1e30f, l_r = 0.f;
  uint4 ka, ka2, va, va2;
  {
    ka  = *(const uint4*)(Kb + (size_t)krow * kvs + kcol);
    ka2 = *(const uint4*)(Kb + (size_t)(krow + 32) * kvs + kcol);
    va  = *(const uint4*)(Vb + (size_t)vkk * kvs + wave * 8);
    va2 = *(const uint4*)(Vb + (size_t)vkk * kvs + (wave + 4) * 8);
  }
  int c = 0;
  for (int kt = 0; kt < nkt; kt++) {
    // issue next tile's loads (in flight through this whole iteration)
    const int kn = (kt + 1 < nkt) ? (kt + 1) * 64 : kt * 64;
    uint4 na  = *(const uint4*)(Kb + (size_t)(kn + krow) * kvs + kcol);
    uint4 na2 = *(const uint4*)(Kb + (size_t)(kn + krow + 32) * kvs + kcol);
    uint4 nv  = *(const uint4*)(Vb + (size_t)(kn + vkk) * kvs + wave * 8);
    uint4 nv2 = *(const uint4*)(Vb + (size_t)(kn + vkk) * kvs + (wave + 4) * 8);
    // stage current tile (vmcnt wait covers loads issued one iteration ago)
    *(uint4*)&Ks[c][krow][kcol]      = ka;
    *(uint4*)&Ks[c][krow + 32][kcol] = ka2;
    { U128 u; u.u = va;  for (int j = 0; j < 8; j++) Vt[c][wave * 8 + j][vkk] = pv_bits(u.h[j]); }
    { U128 u; u.u = va2; for (int j = 0; j < 8; j++) Vt[c][(wave + 4) * 8 + j][vkk] = pv_bits(u.h[j]); }
    __syncthreads();
    // S^T = K Q^T : C-layout row k=nb*16+quad*4+r, col q=lrow
    f32x4 st[4] = {};
    for (int ks = 0; ks < 2; ks++)
      for (int nb = 0; nb < 4; nb++) {
        bf16x8 kf = *(const bf16x8*)&Ks[c][nb * 16 + lrow][ks * 32 + quad * 8];
        st[nb] = __builtin_amdgcn_mfma_f32_16x16x32_bf16(kf, qf[ks], st[nb], 0, 0, 0);
      }
    // causal mask + in-lane max over this lane's 16 k-values
    float pm = -1e30f;
    for (int nb = 0; nb < 4; nb++)
      for (int r = 0; r < 4; r++) {
        float s = st[nb][r];
        if (CAUSAL && kt == qt)
          if (nb * 16 + quad * 4 + r > wm16 + lrow) s = -1e30f;
        st[nb][r] = s;
        pm = fmaxf(pm, s);
      }
    pm = fmaxf(pm, __shfl_xor(pm, 16));
    pm = fmaxf(pm, __shfl_xor(pm, 32));
    float mn = fmaxf(m_r, pm);
    float alpha = __expf(m_r - mn);
    m_r = mn;
    float rs = 0.f;
    PV4 pf[4];
    for (int nb = 0; nb < 4; nb++) {
      float p0 = __expf(st[nb][0] - mn), p1 = __expf(st[nb][1] - mn);
      float p2 = __expf(st[nb][2] - mn), p3 = __expf(st[nb][3] - mn);
      rs += (p0 + p1) + (p2 + p3);
      pf[nb] = pack4(p0, p1, p2, p3);
    }
    rs += __shfl_xor(rs, 16);
    rs += __shfl_xor(rs, 32);
    l_r = l_r * alpha + rs;
    for (int ni = 0; ni < 4; ni++)
      for (int r = 0; r < 4; r++) acc_o[ni][r] *= alpha;
    // O^T += V^T P^T  (A = V^T frag from LDS b64, B = P frag from registers)
    for (int nb = 0; nb < 4; nb++)
      for (int ni = 0; ni < 4; ni++) {
        PV4 vf; vf.u = *(const uint2*)&Vt[c][ni * 16 + lrow][nb * 16 + quad * 4];
        acc_o[ni] = mfma16(vf, pf[nb], acc_o[ni]);
      }
    ka = na; ka2 = na2; va = nv; va2 = nv2;
    c ^= 1;
  }
  const float linv = 1.f / fmaxf(l_r, 1e-30f);
  float* orow = O + (size_t)b * Lq * DMODEL + (size_t)(q0 + wm16 + lrow) * DMODEL + h * DHEAD;
  for (int ni = 0; ni < 4; ni++) {
    float4 v = { acc_o[ni][0] * linv, acc_o[ni][1] * linv,
                 acc_o[ni][2] * linv, acc_o[ni][3] * linv };
    *(float4*)(orow + ni * 16 + quad * 4) = v;
  }
}

// ---------------- residual(ResT + fp32) + LayerNorm -> OutT ----------------
template<typename ResT, typename OutT>
__global__ __launch_bounds__(256) void k_ln_add(const ResT* __restrict__ a,
    const float* __restrict__ bres, const float* __restrict__ g,
    const float* __restrict__ be, OutT* __restrict__ out) {
  __shared__ float red[2][4];
  const int r = blockIdx.x, t = threadIdx.x;
  const size_t base = (size_t)r * DMODEL + t * 4;
  float x[4];
  for (int i = 0; i < 4; i++) x[i] = (float)a[base + i] + bres[base + i];
  float s  = x[0] + x[1] + x[2] + x[3];
  float s2 = x[0]*x[0] + x[1]*x[1] + x[2]*x[2] + x[3]*x[3];
  for (int off = 32; off > 0; off >>= 1) {
    s  += __shfl_down(s, off);
    s2 += __shfl_down(s2, off);
  }
  if ((t & 63) == 0) { red[0][t >> 6] = s; red[1][t >> 6] = s2; }
  __syncthreads();
  s  = red[0][0] + red[0][1] + red[0][2] + red[0][3];
  s2 = red[1][0] + red[1][1] + red[1][2] + red[1][3];
  const float mean = s * (1.f / DMODEL);
  const float var  = s2 * (1.f / DMODEL) - mean * mean;
  const float rstd = rsqrtf(var + 1e-5f);
  for (int i = 0; i < 4; i++)
    out[base + i] = (OutT)((x[i] - mean) * rstd * g[t * 4 + i] + be[t * 4 + i]);
}

extern "C" void kernel_launch(void* const* d_in, const int* in_sizes, int n_in,
                              void* d_out, int out_size, void* d_ws, size_t ws_size,
                              hipStream_t stream) {
  (void)in_sizes; (void)n_in; (void)out_size; (void)ws_size;
  const float* dec   = (const float*)d_in[0];
  const float* enc   = (const float*)d_in[1];
  const float* m_wq  = (const float*)d_in[2];
  const float* m_bq  = (const float*)d_in[3];
  const float* m_wk  = (const float*)d_in[4];
  const float* m_bk  = (const float*)d_in[5];
  const float* m_wv  = (const float*)d_in[6];
  const float* m_bv  = (const float*)d_in[7];
  const float* c_wq  = (const float*)d_in[8];
  const float* c_bq  = (const float*)d_in[9];
  const float* c_wk  = (const float*)d_in[10];
  const float* c_bk  = (const float*)d_in[11];
  const float* c_wv  = (const float*)d_in[12];
  const float* c_bv  = (const float*)d_in[13];
  const float* ff_w1 = (const float*)d_in[14];
  const float* ff_b1 = (const float*)d_in[15];
  const float* ff_w2 = (const float*)d_in[16];
  const float* ff_b2 = (const float*)d_in[17];
  const float* ln1_g = (const float*)d_in[18];
  const float* ln1_b = (const float*)d_in[19];
  const float* ln2_g = (const float*)d_in[20];
  const float* ln2_b = (const float*)d_in[21];

  // workspace (136 MB):
  //  [0,16)   decB -> X1b          [16,32)  encB -> X2b
  //  [32,40)  WB weights (bf16); fp32 bias pack at +38MB
  //  [40,88)  QKV (self) | [40,72) KV (cross) + [72,88) Qc | [40,104) FF
  //  [104,136) AO (fp32)
  char* w = (char*)d_ws;
  __bf16* decB = (__bf16*)(w);
  __bf16* encB = (__bf16*)(w + (16ull << 20));
  __bf16* X1b  = decB;
  __bf16* X2b  = encB;
  __bf16* WB   = (__bf16*)(w + (32ull << 20));
  float*  BP   = (float*) (w + (38ull << 20));
  __bf16* QKV  = (__bf16*)(w + (40ull << 20));
  __bf16* KV   = (__bf16*)(w + (40ull << 20));
  __bf16* Qc   = (__bf16*)(w + (72ull << 20));
  __bf16* FF   = (__bf16*)(w + (40ull << 20));
  float*  AO   = (float*) (w + (104ull << 20));
  float* out = (float*)d_out;

  const int M = 8192, NTOK = M * DMODEL;
  dim3 blk(256);
  dim3 gC(NTOK / 1024);
  dim3 gT6(2, 32, 16);    // per-head weight transpose [16][1024][64] -> [16][64][1024]
  dim3 gA(16, 128);
  dim3 gL(M);

  k_cast<<<gC, blk, 0, stream>>>(dec, decB, NTOK);
  k_cast<<<gC, blk, 0, stream>>>(enc, encB, NTOK);

  // ---- masked self-attention: fused QKV projection (N=3072) ----
  k_transpose<<<gT6, blk, 0, stream>>>(m_wq, WB, 1024, 64);
  k_transpose<<<gT6, blk, 0, stream>>>(m_wk, WB + (1 << 20), 1024, 64);
  k_transpose<<<gT6, blk, 0, stream>>>(m_wv, WB + (2 << 20), 1024, 64);
  k_pack<<<dim3(12), blk, 0, stream>>>(BP, m_bq, m_bk, m_bv, 1024);
  k_gemm<false, __bf16><<<dim3(24, 64), blk, 0, stream>>>(decB, WB, BP, QKV, M, 3072, 1024);
  k_attn<true><<<gA, blk, 0, stream>>>(QKV, QKV + 1024, QKV + 2048, AO, 1024, 1024, 3072, 3072);
  k_ln_add<float, __bf16><<<gL, blk, 0, stream>>>(dec, AO, ln1_g, ln1_b, X1b);  // decB dead

  // ---- cross-attention: fused KV (N=2048, enc) + Q (X1b) ----
  k_transpose<<<gT6, blk, 0, stream>>>(c_wk, WB, 1024, 64);
  k_transpose<<<gT6, blk, 0, stream>>>(c_wv, WB + (1 << 20), 1024, 64);
  k_transpose<<<gT6, blk, 0, stream>>>(c_wq, WB + (2 << 20), 1024, 64);
  k_pack<<<dim3(8), blk, 0, stream>>>(BP, c_bk, c_bv, c_bv, 1024);
  k_gemm<false, __bf16><<<dim3(16, 64), blk, 0, stream>>>(encB, WB, BP, KV, M, 2048, 1024);
  k_gemm<false, __bf16><<<dim3(8, 64), blk, 0, stream>>>(X1b, WB + (2 << 20), c_bq, Qc, M, 1024, 1024);
  k_attn<false><<<gA, blk, 0, stream>>>(Qc, KV, KV + 1024, AO, 1024, 1024, 1024, 2048);
  k_ln_add<__bf16, __bf16><<<gL, blk, 0, stream>>>(X1b, AO, ln2_g, ln2_b, X2b);  // encB dead

  // ---- FFN (QKV/KV/Qc dead -> FF overlays [40,104)) ----
  k_transpose<<<dim3(128, 32, 1), blk, 0, stream>>>(ff_w1, WB, 1024, 4096);
  k_gemm<true, __bf16><<<dim3(32, 64), blk, 0, stream>>>(X2b, WB, ff_b1, FF, M, 4096, 1024);
  k_transpose<<<dim3(32, 128, 1), blk, 0, stream>>>(ff_w2, WB, 4096, 1024);
  k_gemm<false, float><<<dim3(8, 64), blk, 0, stream>>>(FF, WB, ff_b2, AO, M, 1024, 4096);
  k_ln_add<__bf16, float><<<gL, blk, 0, stream>>>(X2b, AO, ln2_g, ln2_b, out);
}

// Round 6
// 688.286 us; speedup vs baseline: 1.3384x; 1.0450x over previous
//
#include <hip/hip_runtime.h>
#include <hip/hip_bf16.h>
#include <cstdint>

typedef __bf16 bf16x8 __attribute__((ext_vector_type(8)));
typedef __bf16 bf16x4 __attribute__((ext_vector_type(4)));
typedef short  short4v __attribute__((ext_vector_type(4)));
typedef _Float16 f16x4 __attribute__((ext_vector_type(4)));
typedef float f32x4 __attribute__((ext_vector_type(4)));

union U128 { uint4 u; __bf16 h[8]; };
union U64  { uint2 u; __bf16 h[4]; };
union PV4  { uint2 u; bf16x4 b; short4v s; f16x4 f; };

#define DMODEL 1024
#define NHEAD  16
#define DHEAD  64

// ---- 16x16x16 MFMA selection for the PV step (P/V as 4x16-bit per lane) ----
#if __has_builtin(__builtin_amdgcn_mfma_f32_16x16x16_bf16)
#define PV_F16 0
__device__ __forceinline__ f32x4 mfma16(PV4 a, PV4 b, f32x4 c) {
  return __builtin_amdgcn_mfma_f32_16x16x16_bf16(a.b, b.b, c, 0, 0, 0);
}
#elif __has_builtin(__builtin_amdgcn_mfma_f32_16x16x16bf16_1k)
#define PV_F16 0
__device__ __forceinline__ f32x4 mfma16(PV4 a, PV4 b, f32x4 c) {
  return __builtin_amdgcn_mfma_f32_16x16x16bf16_1k(a.s, b.s, c, 0, 0, 0);
}
#else
#define PV_F16 1
__device__ __forceinline__ f32x4 mfma16(PV4 a, PV4 b, f32x4 c) {
  return __builtin_amdgcn_mfma_f32_16x16x16f16(a.f, b.f, c, 0, 0, 0);
}
#endif

__device__ __forceinline__ uint16_t pv_bits(__bf16 v) {
#if PV_F16
  union { _Float16 f; uint16_t u; } x; x.f = (_Float16)(float)v; return x.u;
#else
  union { __bf16 b; uint16_t u; } x; x.b = v; return x.u;
#endif
}

__device__ __forceinline__ PV4 pack4(float a, float b, float c, float d) {
  PV4 r;
#if PV_F16
  r.f = (f16x4){(_Float16)a, (_Float16)b, (_Float16)c, (_Float16)d};
#else
  r.b = (bf16x4){(__bf16)a, (__bf16)b, (__bf16)c, (__bf16)d};
#endif
  return r;
}

__device__ __forceinline__ void async_copy16(const void* g, void* l) {
  __builtin_amdgcn_global_load_lds(
      (const __attribute__((address_space(1))) void*)g,
      (__attribute__((address_space(3))) void*)l, 16, 0, 0);
}

// ---------------- fused fp32 -> bf16 cast of two buffers ----------------
__global__ __launch_bounds__(256) void k_cast2(const float* __restrict__ a,
    const float* __restrict__ b, __bf16* __restrict__ da,
    __bf16* __restrict__ db, int n) {
  int i = (blockIdx.x * 256 + threadIdx.x) * 4;
  const float* s = a; __bf16* d = da;
  if (i >= n) { s = b; d = db; i -= n; }
  float4 v = *(const float4*)(s + i);
  U64 o;
  o.h[0] = (__bf16)v.x; o.h[1] = (__bf16)v.y;
  o.h[2] = (__bf16)v.z; o.h[3] = (__bf16)v.w;
  *(uint2*)(d + i) = o.u;
}

// ---------------- pack up to 3 fp32 bias vectors (n each) into dst ----------------
__global__ __launch_bounds__(256) void k_pack(float* __restrict__ dst,
    const float* __restrict__ s0, const float* __restrict__ s1,
    const float* __restrict__ s2, int n) {
  int i = blockIdx.x * 256 + threadIdx.x;
  if (i < n) dst[i] = s0[i];
  else if (i < 2 * n) dst[i] = s1[i - n];
  else if (i < 3 * n) dst[i] = s2[i - 2 * n];
}

// ------------- batched 32x32 transpose + cast: src[z][R][C] f32 -> dst[z][C][R] bf16 -------------
__global__ __launch_bounds__(256) void k_transpose(const float* __restrict__ src,
    __bf16* __restrict__ dst, int R, int C) {
  __shared__ __bf16 tile[32][33];
  src += (size_t)blockIdx.z * R * C;
  dst += (size_t)blockIdx.z * R * C;
  int c0 = blockIdx.x * 32, r0 = blockIdx.y * 32;
  int tx = threadIdx.x & 31, ty = threadIdx.x >> 5;
  for (int i = ty; i < 32; i += 8)
    tile[i][tx] = (__bf16)src[(size_t)(r0 + i) * C + (c0 + tx)];
  __syncthreads();
  for (int i = ty; i < 32; i += 8)
    dst[(size_t)(c0 + i) * R + (r0 + tx)] = tile[tx][i];
}

// ------------- 3-source per-head transpose: srcN[16][R][C] f32 -> dst[z][C][R] bf16, z=src*16+head
__global__ __launch_bounds__(256) void k_transpose3(const float* __restrict__ s0,
    const float* __restrict__ s1, const float* __restrict__ s2,
    __bf16* __restrict__ dst, int R, int C) {
  __shared__ __bf16 tile[32][33];
  int z = blockIdx.z;
  const float* src = (z < 16) ? s0 : (z < 32) ? s1 : s2;
  src += (size_t)(z & 15) * R * C;
  dst += (size_t)z * R * C;
  int c0 = blockIdx.x * 32, r0 = blockIdx.y * 32;
  int tx = threadIdx.x & 31, ty = threadIdx.x >> 5;
  for (int i = ty; i < 32; i += 8)
    tile[i][tx] = (__bf16)src[(size_t)(r0 + i) * C + (c0 + tx)];
  __syncthreads();
  for (int i = ty; i < 32; i += 8)
    dst[(size_t)(c0 + i) * R + (r0 + tx)] = tile[tx][i];
}

// ---------------- bf16 TN GEMM: C[M,N] = A[M,K] * Bt[N,K]^T + bias ----------------
// 128x128 tile, BK=64, global_load_lds staging, 16B-granule XOR swizzle.
template<bool RELU, typename OutT>
__global__ __launch_bounds__(256, 3) void k_gemm(const __bf16* __restrict__ A,
    const __bf16* __restrict__ Bt, const float* __restrict__ bias,
    OutT* __restrict__ C, int M, int N, int K) {
  __shared__ __bf16 As[128][64];
  __shared__ __bf16 Bs[128][64];
  const int m0 = blockIdx.y * 128, n0 = blockIdx.x * 128;
  const int t = threadIdx.x;
  const int wave = t >> 6, lane = t & 63;
  const int wm = (wave & 1) * 64, wn = (wave >> 1) * 64;
  const int lrow = lane & 15, quad = lane >> 4;
  const int r8 = lane >> 3;
  const int gG = (lane & 7) ^ (r8 & 7);
  const __bf16* Ap[4]; const __bf16* Bp[4];
  __bf16* lA[4]; __bf16* lB[4];
  for (int j = 0; j < 4; j++) {
    int rr = wave * 8 + j * 32 + r8;
    Ap[j] = A  + (size_t)(m0 + rr) * K + gG * 8;
    Bp[j] = Bt + (size_t)(n0 + rr) * K + gG * 8;
    lA[j] = &As[wave * 8 + j * 32][0];
    lB[j] = &Bs[wave * 8 + j * 32][0];
  }
  f32x4 acc[4][4] = {};
  for (int k0 = 0; k0 < K; k0 += 64) {
    __syncthreads();
    for (int j = 0; j < 4; j++) {
      async_copy16(Ap[j] + k0, lA[j]);
      async_copy16(Bp[j] + k0, lB[j]);
    }
    __syncthreads();
    for (int ks = 0; ks < 2; ks++) {
      bf16x8 af[4], bfv[4];
      for (int i = 0; i < 4; i++) {
        int ra = wm + i * 16 + lrow, rb = wn + i * 16 + lrow;
        af[i]  = *(const bf16x8*)&As[ra][(((ks * 4 + quad) ^ (ra & 7))) * 8];
        bfv[i] = *(const bf16x8*)&Bs[rb][(((ks * 4 + quad) ^ (rb & 7))) * 8];
      }
      for (int mi = 0; mi < 4; mi++)
        for (int ni = 0; ni < 4; ni++)
          acc[mi][ni] = __builtin_amdgcn_mfma_f32_16x16x32_bf16(af[mi], bfv[ni], acc[mi][ni], 0, 0, 0);
    }
  }
  for (int ni = 0; ni < 4; ni++) {
    int col = n0 + wn + ni * 16 + lrow;
    float bv = bias[col];
    for (int mi = 0; mi < 4; mi++) {
      int row = m0 + wm + mi * 16 + quad * 4;
      for (int r = 0; r < 4; r++) {
        float v = acc[mi][ni][r] + bv;
        if (RELU) v = fmaxf(v, 0.f);
        C[(size_t)(row + r) * N + col] = (OutT)v;
      }
    }
  }
}

// ---------------- fused flash attention v3: 2 q-tiles/block, S^T trick, register PV ----------
// grid (Lq/128, B*H). Causal: block bx covers q-tiles (bx, NT-1-bx) — compute-balanced pairing,
// fully-masked sub-tiles skipped via wave-uniform branch. Cross: tiles (2bx, 2bx+1).
// Each wave: 16 q-rows per tile. Softmax in exp2 domain (scale*log2e folded into Q).
template<bool CAUSAL>
__global__ __launch_bounds__(256, 4) void k_attn(const __bf16* __restrict__ Q,
    const __bf16* __restrict__ Kg, const __bf16* __restrict__ Vg,
    float* __restrict__ O, int Lq, int Lk, int qs, int kvs) {
  __shared__ alignas(16) __bf16   Ks[2][64][72];
  __shared__ alignas(16) uint16_t Vt[2][64][72];   // [vd][k]
  const int t = threadIdx.x;
  const int wave = t >> 6, lane = t & 63;
  const int lrow = lane & 15, quad = lane >> 4;
  const int wm16 = wave * 16;
  int qt[2];
  if (CAUSAL) { qt[0] = blockIdx.x; qt[1] = gridDim.x * 2 - 1 - blockIdx.x; }
  else        { qt[0] = blockIdx.x * 2; qt[1] = qt[0] + 1; }
  const int b = blockIdx.y >> 4, h = blockIdx.y & 15;
  const __bf16* Qb = Q  + (size_t)b * Lq * qs  + h * DHEAD;
  const __bf16* Kb = Kg + (size_t)b * Lk * kvs + h * DHEAD;
  const __bf16* Vb = Vg + (size_t)b * Lk * kvs + h * DHEAD;
  // Q B-fragments, scale folded: 0.125 * log2(e) (softmax done in exp2 domain)
  const float qsc = 0.125f * 1.44269504f;
  bf16x8 qf[2][2];
  for (int f = 0; f < 2; f++)
    for (int ks = 0; ks < 2; ks++) {
      U128 u;
      u.u = *(const uint4*)(Qb + (size_t)(qt[f] * 64 + wm16 + lrow) * qs + ks * 32 + quad * 8);
      for (int j = 0; j < 8; j++) u.h[j] = (__bf16)((float)u.h[j] * qsc);
      qf[f][ks] = *(const bf16x8*)u.h;
    }
  const int nkt = CAUSAL ? (qt[1] + 1) : (Lk / 64);
  const int krow = t >> 3, kcol = (t & 7) * 8;
  const int vkk = t & 63;
  f32x4 acc_o[2][4] = {};       // O^T per frag: row vd=ni*16+quad*4+r, col q=lrow
  float m_r[2] = {-1e30f, -1e30f}, l_r[2] = {0.f, 0.f};
  uint4 ka, ka2, va, va2;
  ka  = *(const uint4*)(Kb + (size_t)krow * kvs + kcol);
  ka2 = *(const uint4*)(Kb + (size_t)(krow + 32) * kvs + kcol);
  va  = *(const uint4*)(Vb + (size_t)vkk * kvs + wave * 8);
  va2 = *(const uint4*)(Vb + (size_t)vkk * kvs + (wave + 4) * 8);
  int c = 0;
  for (int kt = 0; kt < nkt; kt++) {
    const int kn = (kt + 1 < nkt) ? (kt + 1) * 64 : kt * 64;
    uint4 na  = *(const uint4*)(Kb + (size_t)(kn + krow) * kvs + kcol);
    uint4 na2 = *(const uint4*)(Kb + (size_t)(kn + krow + 32) * kvs + kcol);
    uint4 nv  = *(const uint4*)(Vb + (size_t)(kn + vkk) * kvs + wave * 8);
    uint4 nv2 = *(const uint4*)(Vb + (size_t)(kn + vkk) * kvs + (wave + 4) * 8);
    *(uint4*)&Ks[c][krow][kcol]      = ka;
    *(uint4*)&Ks[c][krow + 32][kcol] = ka2;
    { U128 u; u.u = va;  for (int j = 0; j < 8; j++) Vt[c][wave * 8 + j][vkk] = pv_bits(u.h[j]); }
    { U128 u; u.u = va2; for (int j = 0; j < 8; j++) Vt[c][(wave + 4) * 8 + j][vkk] = pv_bits(u.h[j]); }
    __syncthreads();
    for (int f = 0; f < 2; f++) {
      if (CAUSAL && kt > qt[f]) continue;   // wave-uniform: fully-masked sub-tile
      // S^T = K Q^T : C-layout row k=nb*16+quad*4+r, col q=lrow  (exp2 domain)
      f32x4 st[4] = {};
      for (int ks = 0; ks < 2; ks++)
        for (int nb = 0; nb < 4; nb++) {
          bf16x8 kf = *(const bf16x8*)&Ks[c][nb * 16 + lrow][ks * 32 + quad * 8];
          st[nb] = __builtin_amdgcn_mfma_f32_16x16x32_bf16(kf, qf[f][ks], st[nb], 0, 0, 0);
        }
      float pm = -1e30f;
      for (int nb = 0; nb < 4; nb++)
        for (int r = 0; r < 4; r++) {
          float s = st[nb][r];
          if (CAUSAL && kt == qt[f])
            if (nb * 16 + quad * 4 + r > wm16 + lrow) s = -1e30f;
          st[nb][r] = s;
          pm = fmaxf(pm, s);
        }
      pm = fmaxf(pm, __shfl_xor(pm, 16));
      pm = fmaxf(pm, __shfl_xor(pm, 32));
      float mn = fmaxf(m_r[f], pm);
      float alpha = exp2f(m_r[f] - mn);
      m_r[f] = mn;
      float rs = 0.f;
      PV4 pf[4];
      for (int nb = 0; nb < 4; nb++) {
        float p0 = exp2f(st[nb][0] - mn), p1 = exp2f(st[nb][1] - mn);
        float p2 = exp2f(st[nb][2] - mn), p3 = exp2f(st[nb][3] - mn);
        rs += (p0 + p1) + (p2 + p3);
        pf[nb] = pack4(p0, p1, p2, p3);
      }
      rs += __shfl_xor(rs, 16);
      rs += __shfl_xor(rs, 32);
      l_r[f] = l_r[f] * alpha + rs;
      for (int ni = 0; ni < 4; ni++)
        for (int r = 0; r < 4; r++) acc_o[f][ni][r] *= alpha;
      // O^T += V^T P^T  (A = V^T frag from LDS b64, B = P frag from registers)
      for (int nb = 0; nb < 4; nb++)
        for (int ni = 0; ni < 4; ni++) {
          PV4 vf; vf.u = *(const uint2*)&Vt[c][ni * 16 + lrow][nb * 16 + quad * 4];
          acc_o[f][ni] = mfma16(vf, pf[nb], acc_o[f][ni]);
        }
    }
    ka = na; ka2 = na2; va = nv; va2 = nv2;
    c ^= 1;
  }
  for (int f = 0; f < 2; f++) {
    const float linv = 1.f / fmaxf(l_r[f], 1e-30f);
    float* orow = O + (size_t)b * Lq * DMODEL
                + (size_t)(qt[f] * 64 + wm16 + lrow) * DMODEL + h * DHEAD;
    for (int ni = 0; ni < 4; ni++) {
      float4 v = { acc_o[f][ni][0] * linv, acc_o[f][ni][1] * linv,
                   acc_o[f][ni][2] * linv, acc_o[f][ni][3] * linv };
      *(float4*)(orow + ni * 16 + quad * 4) = v;
    }
  }
}

// ---------------- residual(ResT + fp32) + LayerNorm -> OutT ----------------
template<typename ResT, typename OutT>
__global__ __launch_bounds__(256) void k_ln_add(const ResT* __restrict__ a,
    const float* __restrict__ bres, const float* __restrict__ g,
    const float* __restrict__ be, OutT* __restrict__ out) {
  __shared__ float red[2][4];
  const int r = blockIdx.x, t = threadIdx.x;
  const size_t base = (size_t)r * DMODEL + t * 4;
  float x[4];
  for (int i = 0; i < 4; i++) x[i] = (float)a[base + i] + bres[base + i];
  float s  = x[0] + x[1] + x[2] + x[3];
  float s2 = x[0]*x[0] + x[1]*x[1] + x[2]*x[2] + x[3]*x[3];
  for (int off = 32; off > 0; off >>= 1) {
    s  += __shfl_down(s, off);
    s2 += __shfl_down(s2, off);
  }
  if ((t & 63) == 0) { red[0][t >> 6] = s; red[1][t >> 6] = s2; }
  __syncthreads();
  s  = red[0][0] + red[0][1] + red[0][2] + red[0][3];
  s2 = red[1][0] + red[1][1] + red[1][2] + red[1][3];
  const float mean = s * (1.f / DMODEL);
  const float var  = s2 * (1.f / DMODEL) - mean * mean;
  const float rstd = rsqrtf(var + 1e-5f);
  for (int i = 0; i < 4; i++)
    out[base + i] = (OutT)((x[i] - mean) * rstd * g[t * 4 + i] + be[t * 4 + i]);
}

extern "C" void kernel_launch(void* const* d_in, const int* in_sizes, int n_in,
                              void* d_out, int out_size, void* d_ws, size_t ws_size,
                              hipStream_t stream) {
  (void)in_sizes; (void)n_in; (void)out_size; (void)ws_size;
  const float* dec   = (const float*)d_in[0];
  const float* enc   = (const float*)d_in[1];
  const float* m_wq  = (const float*)d_in[2];
  const float* m_bq  = (const float*)d_in[3];
  const float* m_wk  = (const float*)d_in[4];
  const float* m_bk  = (const float*)d_in[5];
  const float* m_wv  = (const float*)d_in[6];
  const float* m_bv  = (const float*)d_in[7];
  const float* c_wq  = (const float*)d_in[8];
  const float* c_bq  = (const float*)d_in[9];
  const float* c_wk  = (const float*)d_in[10];
  const float* c_bk  = (const float*)d_in[11];
  const float* c_wv  = (const float*)d_in[12];
  const float* c_bv  = (const float*)d_in[13];
  const float* ff_w1 = (const float*)d_in[14];
  const float* ff_b1 = (const float*)d_in[15];
  const float* ff_w2 = (const float*)d_in[16];
  const float* ff_b2 = (const float*)d_in[17];
  const float* ln1_g = (const float*)d_in[18];
  const float* ln1_b = (const float*)d_in[19];
  const float* ln2_g = (const float*)d_in[20];
  const float* ln2_b = (const float*)d_in[21];

  // workspace (136 MB):
  //  [0,16)   decB -> X1b          [16,32)  encB -> X2b
  //  [32,40)  WB weights (bf16); fp32 bias pack at +38MB
  //  [40,88)  QKV (self) | [40,72) KV (cross) + [72,88) Qc | [40,104) FF
  //  [104,136) AO (fp32)
  char* w = (char*)d_ws;
  __bf16* decB = (__bf16*)(w);
  __bf16* encB = (__bf16*)(w + (16ull << 20));
  __bf16* X1b  = decB;
  __bf16* X2b  = encB;
  __bf16* WB   = (__bf16*)(w + (32ull << 20));
  float*  BP   = (float*) (w + (38ull << 20));
  __bf16* QKV  = (__bf16*)(w + (40ull << 20));
  __bf16* KV   = (__bf16*)(w + (40ull << 20));
  __bf16* Qc   = (__bf16*)(w + (72ull << 20));
  __bf16* FF   = (__bf16*)(w + (40ull << 20));
  float*  AO   = (float*) (w + (104ull << 20));
  float* out = (float*)d_out;

  const int M = 8192, NTOK = M * DMODEL;
  dim3 blk(256);
  dim3 gT3(2, 32, 48);    // 3-source per-head weight transpose
  dim3 gA(8, 128);        // attention: 2 q-tiles per block
  dim3 gL(M);

  k_cast2<<<dim3(2 * NTOK / 1024), blk, 0, stream>>>(dec, enc, decB, encB, NTOK);

  // ---- masked self-attention: fused QKV projection (N=3072) ----
  k_transpose3<<<gT3, blk, 0, stream>>>(m_wq, m_wk, m_wv, WB, 1024, 64);
  k_pack<<<dim3(12), blk, 0, stream>>>(BP, m_bq, m_bk, m_bv, 1024);
  k_gemm<false, __bf16><<<dim3(24, 64), blk, 0, stream>>>(decB, WB, BP, QKV, M, 3072, 1024);
  k_attn<true><<<gA, blk, 0, stream>>>(QKV, QKV + 1024, QKV + 2048, AO, 1024, 1024, 3072, 3072);
  k_ln_add<float, __bf16><<<gL, blk, 0, stream>>>(dec, AO, ln1_g, ln1_b, X1b);  // decB dead

  // ---- cross-attention: fused KV (N=2048, enc) + Q (X1b) ----
  k_transpose3<<<gT3, blk, 0, stream>>>(c_wk, c_wv, c_wq, WB, 1024, 64);
  k_pack<<<dim3(8), blk, 0, stream>>>(BP, c_bk, c_bv, c_bv, 1024);
  k_gemm<false, __bf16><<<dim3(16, 64), blk, 0, stream>>>(encB, WB, BP, KV, M, 2048, 1024);
  k_gemm<false, __bf16><<<dim3(8, 64), blk, 0, stream>>>(X1b, WB + (2 << 20), c_bq, Qc, M, 1024, 1024);
  k_attn<false><<<gA, blk, 0, stream>>>(Qc, KV, KV + 1024, AO, 1024, 1024, 1024, 2048);
  k_ln_add<__bf16, __bf16><<<gL, blk, 0, stream>>>(X1b, AO, ln2_g, ln2_b, X2b);  // encB dead

  // ---- FFN (QKV/KV/Qc dead -> FF overlays [40,104)) ----
  k_transpose<<<dim3(128, 32, 1), blk, 0, stream>>>(ff_w1, WB, 1024, 4096);
  k_gemm<true, __bf16><<<dim3(32, 64), blk, 0, stream>>>(X2b, WB, ff_b1, FF, M, 4096, 1024);
  k_transpose<<<dim3(32, 128, 1), blk, 0, stream>>>(ff_w2, WB, 4096, 1024);
  k_gemm<false, float><<<dim3(8, 64), blk, 0, stream>>>(FF, WB, ff_b2, AO, M, 1024, 4096);
  k_ln_add<__bf16, float><<<gL, blk, 0, stream>>>(X2b, AO, ln2_g, ln2_b, out);
}